// Round 1
// baseline (212.084 us; speedup 1.0000x reference)
//
#include <hip/hip_runtime.h>
#include <hip/hip_bf16.h>

typedef __attribute__((ext_vector_type(8))) short short8;
typedef __attribute__((ext_vector_type(4))) float f32x4;
typedef __attribute__((ext_vector_type(4))) float float4v;
typedef __attribute__((ext_vector_type(4))) unsigned short ushort4v;

#define MFMA16(a, b, c) __builtin_amdgcn_mfma_f32_16x16x32_bf16((a), (b), (c), 0, 0, 0)

__device__ __forceinline__ unsigned short f2bf(float f) {
    union { float f; unsigned u; } v; v.f = f;
    unsigned r = v.u + 0x7fffu + ((v.u >> 16) & 1u);
    return (unsigned short)(r >> 16);
}
__device__ __forceinline__ float bf2f(unsigned short h) {
    union { unsigned u; float f; } v; v.u = (unsigned)h << 16;
    return v.f;
}

// ---------------------------------------------------------------------------
// Kernel 1: transpose weights 512x512 fp32 -> bf16, WT[n][k] = W[k][n]
// ---------------------------------------------------------------------------
__global__ __launch_bounds__(256) void wtrans_kernel(
    const float* __restrict__ W0, const float* __restrict__ W1,
    const float* __restrict__ W2, const float* __restrict__ W3,
    unsigned short* __restrict__ T0, unsigned short* __restrict__ T1,
    unsigned short* __restrict__ T2, unsigned short* __restrict__ T3)
{
    const int z = blockIdx.z;
    const float* W = (z == 0) ? W0 : (z == 1) ? W1 : (z == 2) ? W2 : W3;
    unsigned short* T = (z == 0) ? T0 : (z == 1) ? T1 : (z == 2) ? T2 : T3;

    __shared__ unsigned short tile[64][72];
    const int k0 = blockIdx.x * 64, n0 = blockIdx.y * 64;
    const int t = threadIdx.x;

#pragma unroll
    for (int p = 0; p < 4; ++p) {
        int idx = p * 256 + t;
        int k = idx >> 4, c4 = idx & 15;
        float4v v = *(const float4v*)(W + (size_t)(k0 + k) * 512 + n0 + c4 * 4);
#pragma unroll
        for (int j = 0; j < 4; ++j) tile[k][c4 * 4 + j] = f2bf(v[j]);
    }
    __syncthreads();
#pragma unroll
    for (int p = 0; p < 2; ++p) {
        int idx = p * 256 + t;
        int n = idx >> 3, c = idx & 7;
        short8 o;
#pragma unroll
        for (int j = 0; j < 8; ++j) o[j] = (short)tile[c * 8 + j][n];
        *(short8*)(T + (size_t)(n0 + n) * 512 + k0 + c * 8) = o;
    }
}

// ---------------------------------------------------------------------------
// Kernel 2: fused q/k/v projection GEMM. A fp32 (16384x512), WT bf16 (n-major),
// out bf16 (16384x512). z=0: q from Q; z=1: k from K; z=2: v from K.
// Tile 128x128, BK=64, 4 waves (2x2), each wave 64x64 (4x4 frags of 16x16x32).
// LDS tiles [128 rows][64 k] bf16, XOR-swizzled 16B blocks: blk ^= (row & 7).
// ---------------------------------------------------------------------------
__global__ __launch_bounds__(256) void proj_kernel(
    const float* __restrict__ Q, const float* __restrict__ Kin,
    const unsigned short* __restrict__ WqT, const unsigned short* __restrict__ WkT,
    const unsigned short* __restrict__ WvT,
    const float* __restrict__ bq, const float* __restrict__ bk, const float* __restrict__ bv,
    unsigned short* __restrict__ qb, unsigned short* __restrict__ kb,
    unsigned short* __restrict__ vb)
{
    const int z = blockIdx.z;
    const float* A = (z == 0) ? Q : Kin;
    const unsigned short* WT = (z == 0) ? WqT : (z == 1) ? WkT : WvT;
    const float* bias = (z == 0) ? bq : (z == 1) ? bk : bv;
    unsigned short* out = (z == 0) ? qb : (z == 1) ? kb : vb;

    __shared__ unsigned short Al[128 * 64];
    __shared__ unsigned short Bl[128 * 64];

    const int t = threadIdx.x;
    const int lane = t & 63, wid = t >> 6;
    const int wm = wid >> 1, wn = wid & 1;
    const int l15 = lane & 15, grp = lane >> 4;
    const int rowbase = blockIdx.y * 128;
    const int colbase = blockIdx.x * 128;

    f32x4 acc[4][4];
#pragma unroll
    for (int i = 0; i < 4; ++i)
#pragma unroll
        for (int j = 0; j < 4; ++j) acc[i][j] = (f32x4){0.f, 0.f, 0.f, 0.f};

    for (int kt = 0; kt < 8; ++kt) {
        // stage A: 128 x 64 fp32 -> bf16
#pragma unroll
        for (int p = 0; p < 8; ++p) {
            int idx = p * 256 + t;
            int r = idx >> 4, c4 = idx & 15;
            float4v v = *(const float4v*)(A + (size_t)(rowbase + r) * 512 + kt * 64 + c4 * 4);
            unsigned addr = r * 128 + ((((unsigned)c4 >> 1) ^ (r & 7)) << 4) + (c4 & 1) * 8;
            ushort4v w;
            w[0] = f2bf(v[0]); w[1] = f2bf(v[1]); w[2] = f2bf(v[2]); w[3] = f2bf(v[3]);
            *(ushort4v*)((char*)Al + addr) = w;
        }
        // stage B: 128 rows(n) x 64(k) bf16
#pragma unroll
        for (int p = 0; p < 4; ++p) {
            int idx = p * 256 + t;
            int n = idx >> 3, c = idx & 7;
            short8 v = *(const short8*)(WT + (size_t)(colbase + n) * 512 + kt * 64 + c * 8);
            *(short8*)((char*)Bl + n * 128 + ((c ^ (n & 7)) << 4)) = v;
        }
        __syncthreads();
#pragma unroll
        for (int kk = 0; kk < 2; ++kk) {
            short8 af[4], bfr[4];
#pragma unroll
            for (int m = 0; m < 4; ++m) {
                int r = wm * 64 + m * 16 + l15;
                af[m] = *(const short8*)((const char*)Al + r * 128 + (((kk * 4 + grp) ^ (r & 7)) << 4));
            }
#pragma unroll
            for (int n = 0; n < 4; ++n) {
                int r = wn * 64 + n * 16 + l15;
                bfr[n] = *(const short8*)((const char*)Bl + r * 128 + (((kk * 4 + grp) ^ (r & 7)) << 4));
            }
#pragma unroll
            for (int m = 0; m < 4; ++m)
#pragma unroll
                for (int n = 0; n < 4; ++n)
                    acc[m][n] = MFMA16(af[m], bfr[n], acc[m][n]);
        }
        __syncthreads();
    }
    // epilogue: + bias, store bf16
#pragma unroll
    for (int n = 0; n < 4; ++n) {
        int col = colbase + wn * 64 + n * 16 + l15;
        float bvv = bias[col];
#pragma unroll
        for (int m = 0; m < 4; ++m) {
            int row0 = rowbase + wm * 64 + m * 16 + grp * 4;
#pragma unroll
            for (int r = 0; r < 4; ++r)
                out[(size_t)(row0 + r) * 512 + col] = f2bf(acc[m][n][r] + bvv);
        }
    }
}

// ---------------------------------------------------------------------------
// Kernel 3: v (b,key,h*64+d) bf16 -> vT (b,h,d,key) bf16
// ---------------------------------------------------------------------------
__global__ __launch_bounds__(256) void vtrans_kernel(
    const unsigned short* __restrict__ vb, unsigned short* __restrict__ vT)
{
    __shared__ unsigned short tile[64][72];
    const int key0 = blockIdx.x * 64;
    const int h = blockIdx.y;
    const int b = blockIdx.z;
    const int t = threadIdx.x;

#pragma unroll
    for (int p = 0; p < 2; ++p) {
        int idx = p * 256 + t;
        int key = idx >> 3, c = idx & 7;
        short8 v = *(const short8*)(vb + (size_t)(b * 1024 + key0 + key) * 512 + h * 64 + c * 8);
        *(short8*)&tile[key][c * 8] = v;
    }
    __syncthreads();
#pragma unroll
    for (int p = 0; p < 2; ++p) {
        int idx = p * 256 + t;
        int d = idx >> 3, c = idx & 7;
        short8 o;
#pragma unroll
        for (int j = 0; j < 8; ++j) o[j] = (short)tile[c * 8 + j][d];
        *(short8*)(vT + ((size_t)(b * 8 + h) * 64 + d) * 1024 + key0 + c * 8) = o;
    }
}

// ---------------------------------------------------------------------------
// Kernel 4: flash attention per (qtile=64, h, b). 4 waves, wave w owns q rows
// [w*16, w*16+16). Online softmax in-register; P repacked via wave-private LDS.
// Epilogue: Opre = q + attn (bf16).
// ---------------------------------------------------------------------------
__global__ __launch_bounds__(256) void attn_kernel(
    const unsigned short* __restrict__ qb, const unsigned short* __restrict__ kb,
    const unsigned short* __restrict__ vT, unsigned short* __restrict__ Opre)
{
    const int qt = blockIdx.x;  // 16
    const int h  = blockIdx.y;  // 8
    const int b  = blockIdx.z;  // 16
    const int t = threadIdx.x, lane = t & 63, wid = t >> 6;
    const int l15 = lane & 15, grp = lane >> 4;
    const int qbase = qt * 64;

    __shared__ unsigned short Kl[64 * 64];
    __shared__ unsigned short Vl[64 * 64];
    __shared__ unsigned short Pl[4][1024];

    // q A-frags straight from global (16B contiguous per lane)
    const unsigned short* qptr =
        qb + (size_t)(b * 1024 + qbase + wid * 16 + l15) * 512 + h * 64 + grp * 8;
    short8 qf0 = *(const short8*)qptr;
    short8 qf1 = *(const short8*)(qptr + 32);

    f32x4 o[4];
#pragma unroll
    for (int nf = 0; nf < 4; ++nf) o[nf] = (f32x4){0.f, 0.f, 0.f, 0.f};
    float mrun[4], lrun[4];
#pragma unroll
    for (int r = 0; r < 4; ++r) { mrun[r] = -1e30f; lrun[r] = 0.f; }

    const float sc = 0.04419417382415922f;  // 1/sqrt(512)

    for (int kt = 0; kt < 16; ++kt) {
        // stage K tile [64 keys][64 kd] and V^T tile [64 d][64 keys], swizzled
#pragma unroll
        for (int p = 0; p < 2; ++p) {
            int idx = p * 256 + t;
            int key = idx >> 3, c = idx & 7;
            short8 v = *(const short8*)(kb + (size_t)(b * 1024 + kt * 64 + key) * 512 + h * 64 + c * 8);
            *(short8*)((char*)Kl + key * 128 + ((c ^ (key & 7)) << 4)) = v;
        }
#pragma unroll
        for (int p = 0; p < 2; ++p) {
            int idx = p * 256 + t;
            int d = idx >> 3, c = idx & 7;
            short8 v = *(const short8*)(vT + ((size_t)(b * 8 + h) * 64 + d) * 1024 + kt * 64 + c * 8);
            *(short8*)((char*)Vl + d * 128 + ((c ^ (d & 7)) << 4)) = v;
        }
        __syncthreads();

        // S = q . k^T   (D[q][key], q = grp*4+r, key = l15 + 16*nf)
        f32x4 s[4];
#pragma unroll
        for (int nf = 0; nf < 4; ++nf) s[nf] = (f32x4){0.f, 0.f, 0.f, 0.f};
#pragma unroll
        for (int kk = 0; kk < 2; ++kk) {
            short8 qf = kk ? qf1 : qf0;
#pragma unroll
            for (int nf = 0; nf < 4; ++nf) {
                int r = nf * 16 + l15;
                short8 kf = *(const short8*)((const char*)Kl + r * 128 + (((kk * 4 + grp) ^ (r & 7)) << 4));
                s[nf] = MFMA16(qf, kf, s[nf]);
            }
        }
#pragma unroll
        for (int nf = 0; nf < 4; ++nf)
#pragma unroll
            for (int r = 0; r < 4; ++r) s[nf][r] *= sc;

        // online softmax (row = 16 lanes sharing grp; 4 q-rows per lane)
#pragma unroll
        for (int r = 0; r < 4; ++r) {
            float m = fmaxf(fmaxf(s[0][r], s[1][r]), fmaxf(s[2][r], s[3][r]));
#pragma unroll
            for (int ofs = 1; ofs < 16; ofs <<= 1) m = fmaxf(m, __shfl_xor(m, ofs));
            float mnew = fmaxf(mrun[r], m);
            float rs = __expf(mrun[r] - mnew);
            lrun[r] *= rs;
#pragma unroll
            for (int nf = 0; nf < 4; ++nf) o[nf][r] *= rs;
            mrun[r] = mnew;
        }
        // P = exp(s - m) -> bf16 -> wave-private LDS (swizzled rows of 128B)
#pragma unroll
        for (int nf = 0; nf < 4; ++nf) {
#pragma unroll
            for (int r = 0; r < 4; ++r) {
                float p = __expf(s[nf][r] - mrun[r]);
                lrun[r] += p;
                int q = grp * 4 + r;
                int kbyte = (l15 + 16 * nf) * 2;
                unsigned addr = q * 128 + ((((unsigned)kbyte >> 4) ^ (q & 7)) << 4) + (kbyte & 15);
                *(unsigned short*)((char*)Pl[wid] + addr) = f2bf(p);
            }
        }
        // PV: o += P . V   (A = P rows, B = vT rows)
#pragma unroll
        for (int kk = 0; kk < 2; ++kk) {
            short8 pa = *(const short8*)((const char*)Pl[wid] + l15 * 128 + (((kk * 4 + grp) ^ (l15 & 7)) << 4));
#pragma unroll
            for (int nf = 0; nf < 4; ++nf) {
                int vr = nf * 16 + l15;
                short8 vf = *(const short8*)((const char*)Vl + vr * 128 + (((kk * 4 + grp) ^ (vr & 7)) << 4));
                o[nf] = MFMA16(pa, vf, o[nf]);
            }
        }
        __syncthreads();
    }

    float linv[4];
#pragma unroll
    for (int r = 0; r < 4; ++r) {
        float l = lrun[r];
#pragma unroll
        for (int ofs = 1; ofs < 16; ofs <<= 1) l += __shfl_xor(l, ofs);
        linv[r] = 1.f / l;
    }
#pragma unroll
    for (int nf = 0; nf < 4; ++nf) {
#pragma unroll
        for (int r = 0; r < 4; ++r) {
            size_t row = (size_t)(b * 1024 + qbase + wid * 16 + grp * 4 + r);
            int col = h * 64 + l15 + 16 * nf;
            float val = o[nf][r] * linv[r] + bf2f(qb[row * 512 + col]);
            Opre[row * 512 + col] = f2bf(val);
        }
    }
}

// ---------------------------------------------------------------------------
// Kernel 5/7: LayerNorm over rows of 512. One wave per row. OUT_F32 selects
// bf16 (intermediate) vs fp32 (final) output.
// ---------------------------------------------------------------------------
template <int OUT_F32>
__global__ __launch_bounds__(256) void ln_kernel(
    const unsigned short* in, const float* __restrict__ g, const float* __restrict__ be,
    unsigned short* outb, float* outf)
{
    const int wid = threadIdx.x >> 6, lane = threadIdx.x & 63;
    const size_t row = (size_t)blockIdx.x * 4 + wid;
    short8 v = *(const short8*)(in + row * 512 + lane * 8);
    float x[8];
    float sum = 0.f, sq = 0.f;
#pragma unroll
    for (int j = 0; j < 8; ++j) {
        x[j] = bf2f((unsigned short)v[j]);
        sum += x[j];
        sq += x[j] * x[j];
    }
#pragma unroll
    for (int ofs = 1; ofs < 64; ofs <<= 1) {
        sum += __shfl_xor(sum, ofs);
        sq += __shfl_xor(sq, ofs);
    }
    float mean = sum * (1.f / 512.f);
    float var = sq * (1.f / 512.f) - mean * mean;
    float rs = rsqrtf(var + 1e-5f);
    float4v g0 = *(const float4v*)(g + lane * 8);
    float4v g1 = *(const float4v*)(g + lane * 8 + 4);
    float4v b0 = *(const float4v*)(be + lane * 8);
    float4v b1 = *(const float4v*)(be + lane * 8 + 4);
    float y[8];
#pragma unroll
    for (int j = 0; j < 4; ++j) y[j] = (x[j] - mean) * rs * g0[j] + b0[j];
#pragma unroll
    for (int j = 0; j < 4; ++j) y[4 + j] = (x[4 + j] - mean) * rs * g1[j] + b1[j];
    if (OUT_F32) {
        float4v o0, o1;
#pragma unroll
        for (int j = 0; j < 4; ++j) { o0[j] = y[j]; o1[j] = y[4 + j]; }
        *(float4v*)(outf + row * 512 + lane * 8) = o0;
        *(float4v*)(outf + row * 512 + lane * 8 + 4) = o1;
    } else {
        short8 o;
#pragma unroll
        for (int j = 0; j < 8; ++j) o[j] = (short)f2bf(y[j]);
        *(short8*)(outb + row * 512 + lane * 8) = o;
    }
}

// ---------------------------------------------------------------------------
// Kernel 6: O2 = O1 + relu(O1 @ Wo + bo). A bf16, same GEMM structure.
// ---------------------------------------------------------------------------
__global__ __launch_bounds__(256) void ffn_kernel(
    const unsigned short* __restrict__ O1, const unsigned short* __restrict__ WoT,
    const float* __restrict__ bo, unsigned short* __restrict__ O2)
{
    __shared__ unsigned short Al[128 * 64];
    __shared__ unsigned short Bl[128 * 64];

    const int t = threadIdx.x;
    const int lane = t & 63, wid = t >> 6;
    const int wm = wid >> 1, wn = wid & 1;
    const int l15 = lane & 15, grp = lane >> 4;
    const int rowbase = blockIdx.y * 128;
    const int colbase = blockIdx.x * 128;

    f32x4 acc[4][4];
#pragma unroll
    for (int i = 0; i < 4; ++i)
#pragma unroll
        for (int j = 0; j < 4; ++j) acc[i][j] = (f32x4){0.f, 0.f, 0.f, 0.f};

    for (int kt = 0; kt < 8; ++kt) {
#pragma unroll
        for (int p = 0; p < 4; ++p) {
            int idx = p * 256 + t;
            int r = idx >> 3, c = idx & 7;
            short8 v = *(const short8*)(O1 + (size_t)(rowbase + r) * 512 + kt * 64 + c * 8);
            *(short8*)((char*)Al + r * 128 + ((c ^ (r & 7)) << 4)) = v;
        }
#pragma unroll
        for (int p = 0; p < 4; ++p) {
            int idx = p * 256 + t;
            int n = idx >> 3, c = idx & 7;
            short8 v = *(const short8*)(WoT + (size_t)(colbase + n) * 512 + kt * 64 + c * 8);
            *(short8*)((char*)Bl + n * 128 + ((c ^ (n & 7)) << 4)) = v;
        }
        __syncthreads();
#pragma unroll
        for (int kk = 0; kk < 2; ++kk) {
            short8 af[4], bfr[4];
#pragma unroll
            for (int m = 0; m < 4; ++m) {
                int r = wm * 64 + m * 16 + l15;
                af[m] = *(const short8*)((const char*)Al + r * 128 + (((kk * 4 + grp) ^ (r & 7)) << 4));
            }
#pragma unroll
            for (int n = 0; n < 4; ++n) {
                int r = wn * 64 + n * 16 + l15;
                bfr[n] = *(const short8*)((const char*)Bl + r * 128 + (((kk * 4 + grp) ^ (r & 7)) << 4));
            }
#pragma unroll
            for (int m = 0; m < 4; ++m)
#pragma unroll
                for (int n = 0; n < 4; ++n)
                    acc[m][n] = MFMA16(af[m], bfr[n], acc[m][n]);
        }
        __syncthreads();
    }
#pragma unroll
    for (int n = 0; n < 4; ++n) {
        int col = colbase + wn * 64 + n * 16 + l15;
        float bvv = bo[col];
#pragma unroll
        for (int m = 0; m < 4; ++m) {
            int row0 = rowbase + wm * 64 + m * 16 + grp * 4;
#pragma unroll
            for (int r = 0; r < 4; ++r) {
                size_t row = (size_t)(row0 + r);
                float val = fmaxf(acc[m][n][r] + bvv, 0.f);
                float resid = bf2f(O1[row * 512 + col]);
                O2[row * 512 + col] = f2bf(resid + val);
            }
        }
    }
}

// ---------------------------------------------------------------------------
extern "C" void kernel_launch(void* const* d_in, const int* in_sizes, int n_in,
                              void* d_out, int out_size, void* d_ws, size_t ws_size,
                              hipStream_t stream)
{
    const float* Q   = (const float*)d_in[0];
    const float* Kin = (const float*)d_in[1];
    const float* Wq  = (const float*)d_in[2];
    const float* bq  = (const float*)d_in[3];
    const float* Wk  = (const float*)d_in[4];
    const float* bk  = (const float*)d_in[5];
    const float* Wv  = (const float*)d_in[6];
    const float* bv  = (const float*)d_in[7];
    const float* Wo  = (const float*)d_in[8];
    const float* bo  = (const float*)d_in[9];
    const float* g0  = (const float*)d_in[10];
    const float* b0  = (const float*)d_in[11];
    const float* g1  = (const float*)d_in[12];
    const float* b1  = (const float*)d_in[13];
    float* out = (float*)d_out;

    unsigned short* ws = (unsigned short*)d_ws;
    const size_t WSZ = 512 * 512;        // 0.25M elems
    const size_t BIG = 16384 * 512;      // 8.4M elems
    unsigned short* WqT  = ws;
    unsigned short* WkT  = WqT + WSZ;
    unsigned short* WvT  = WkT + WSZ;
    unsigned short* WoT  = WvT + WSZ;
    unsigned short* qb   = WoT + WSZ;
    unsigned short* kb   = qb + BIG;
    unsigned short* vb   = kb + BIG;
    unsigned short* vT   = vb + BIG;
    unsigned short* Opre = vT + BIG;
    unsigned short* O1   = Opre;   // LN0 in place
    unsigned short* O2   = vb;     // vb dead after vtrans/attn

    wtrans_kernel<<<dim3(8, 8, 4), 256, 0, stream>>>(Wq, Wk, Wv, Wo, WqT, WkT, WvT, WoT);
    proj_kernel<<<dim3(4, 128, 3), 256, 0, stream>>>(Q, Kin, WqT, WkT, WvT, bq, bk, bv, qb, kb, vb);
    vtrans_kernel<<<dim3(16, 8, 16), 256, 0, stream>>>(vb, vT);
    attn_kernel<<<dim3(16, 8, 16), 256, 0, stream>>>(qb, kb, vT, Opre);
    ln_kernel<0><<<dim3(4096), 256, 0, stream>>>(Opre, g0, b0, O1, nullptr);
    ffn_kernel<<<dim3(4, 128), 256, 0, stream>>>(O1, WoT, bo, O2);
    ln_kernel<1><<<dim3(4096), 256, 0, stream>>>(O2, g1, b1, nullptr, out);
}

// Round 2
// 171.618 us; speedup vs baseline: 1.2358x; 1.2358x over previous
//
#include <hip/hip_runtime.h>
#include <hip/hip_bf16.h>

typedef __attribute__((ext_vector_type(8))) short short8;
typedef __attribute__((ext_vector_type(4))) float f32x4;
typedef __attribute__((ext_vector_type(4))) float float4v;
typedef __attribute__((ext_vector_type(4))) unsigned short ushort4v;
typedef __attribute__((ext_vector_type(2))) unsigned int uint2v;

#define MFMA16(a, b, c) __builtin_amdgcn_mfma_f32_16x16x32_bf16((a), (b), (c), 0, 0, 0)

__device__ __forceinline__ unsigned short f2bf(float f) {
    union { float f; unsigned u; } v; v.f = f;
    unsigned r = v.u + 0x7fffu + ((v.u >> 16) & 1u);
    return (unsigned short)(r >> 16);
}
__device__ __forceinline__ float bf2f(unsigned short h) {
    union { unsigned u; float f; } v; v.u = (unsigned)h << 16;
    return v.f;
}
__device__ __forceinline__ unsigned cvt_pk_bf16(float lo, float hi) {
    unsigned r;
    asm("v_cvt_pk_bf16_f32 %0, %1, %2" : "=v"(r) : "v"(lo), "v"(hi));
    return r;
}

// ---------------------------------------------------------------------------
// Kernel 0: fp32 -> bf16 elementwise convert (Q and K inputs). 8 elems/thread.
// ---------------------------------------------------------------------------
__global__ __launch_bounds__(256) void cvt_kernel(
    const float* __restrict__ Q, const float* __restrict__ K,
    unsigned short* __restrict__ Qb, unsigned short* __restrict__ Kb)
{
    const float* in = blockIdx.z ? K : Q;
    unsigned short* out = blockIdx.z ? Kb : Qb;
    size_t i = ((size_t)blockIdx.x * 256 + threadIdx.x) * 8;
    float4v v0 = *(const float4v*)(in + i);
    float4v v1 = *(const float4v*)(in + i + 4);
    short8 o;
#pragma unroll
    for (int j = 0; j < 4; ++j) { o[j] = (short)f2bf(v0[j]); o[4 + j] = (short)f2bf(v1[j]); }
    *(short8*)(out + i) = o;
}

// ---------------------------------------------------------------------------
// Kernel 1: transpose weights 512x512 fp32 -> bf16, WT[n][k] = W[k][n]
// ---------------------------------------------------------------------------
__global__ __launch_bounds__(256) void wtrans_kernel(
    const float* __restrict__ W0, const float* __restrict__ W1,
    const float* __restrict__ W2, const float* __restrict__ W3,
    unsigned short* __restrict__ T0, unsigned short* __restrict__ T1,
    unsigned short* __restrict__ T2, unsigned short* __restrict__ T3)
{
    const int z = blockIdx.z;
    const float* W = (z == 0) ? W0 : (z == 1) ? W1 : (z == 2) ? W2 : W3;
    unsigned short* T = (z == 0) ? T0 : (z == 1) ? T1 : (z == 2) ? T2 : T3;

    __shared__ unsigned short tile[64][72];
    const int k0 = blockIdx.x * 64, n0 = blockIdx.y * 64;
    const int t = threadIdx.x;

#pragma unroll
    for (int p = 0; p < 4; ++p) {
        int idx = p * 256 + t;
        int k = idx >> 4, c4 = idx & 15;
        float4v v = *(const float4v*)(W + (size_t)(k0 + k) * 512 + n0 + c4 * 4);
#pragma unroll
        for (int j = 0; j < 4; ++j) tile[k][c4 * 4 + j] = f2bf(v[j]);
    }
    __syncthreads();
#pragma unroll
    for (int p = 0; p < 2; ++p) {
        int idx = p * 256 + t;
        int n = idx >> 3, c = idx & 7;
        short8 o;
#pragma unroll
        for (int j = 0; j < 8; ++j) o[j] = (short)tile[c * 8 + j][n];
        *(short8*)(T + (size_t)(n0 + n) * 512 + k0 + c * 8) = o;
    }
}

// ---------------------------------------------------------------------------
// Kernel 2: fused q/k/v projection GEMM, A bf16 now (pre-converted).
// Tile 128x128, BK=64, 4 waves (2x2). LDS XOR-swizzled 16B blocks.
// ---------------------------------------------------------------------------
__global__ __launch_bounds__(256) void proj_kernel(
    const unsigned short* __restrict__ Qb, const unsigned short* __restrict__ Kb,
    const unsigned short* __restrict__ WqT, const unsigned short* __restrict__ WkT,
    const unsigned short* __restrict__ WvT,
    const float* __restrict__ bq, const float* __restrict__ bk, const float* __restrict__ bv,
    unsigned short* __restrict__ qb, unsigned short* __restrict__ kb,
    unsigned short* __restrict__ vb)
{
    const int z = blockIdx.z;
    const unsigned short* A = (z == 0) ? Qb : Kb;
    const unsigned short* WT = (z == 0) ? WqT : (z == 1) ? WkT : WvT;
    const float* bias = (z == 0) ? bq : (z == 1) ? bk : bv;
    unsigned short* out = (z == 0) ? qb : (z == 1) ? kb : vb;

    __shared__ unsigned short Al[128 * 64];
    __shared__ unsigned short Bl[128 * 64];

    const int t = threadIdx.x;
    const int lane = t & 63, wid = t >> 6;
    const int wm = wid >> 1, wn = wid & 1;
    const int l15 = lane & 15, grp = lane >> 4;
    const int rowbase = blockIdx.y * 128;
    const int colbase = blockIdx.x * 128;

    f32x4 acc[4][4];
#pragma unroll
    for (int i = 0; i < 4; ++i)
#pragma unroll
        for (int j = 0; j < 4; ++j) acc[i][j] = (f32x4){0.f, 0.f, 0.f, 0.f};

    for (int kt = 0; kt < 8; ++kt) {
#pragma unroll
        for (int p = 0; p < 4; ++p) {
            int idx = p * 256 + t;
            int r = idx >> 3, c = idx & 7;
            short8 v = *(const short8*)(A + (size_t)(rowbase + r) * 512 + kt * 64 + c * 8);
            *(short8*)((char*)Al + r * 128 + ((c ^ (r & 7)) << 4)) = v;
        }
#pragma unroll
        for (int p = 0; p < 4; ++p) {
            int idx = p * 256 + t;
            int n = idx >> 3, c = idx & 7;
            short8 v = *(const short8*)(WT + (size_t)(colbase + n) * 512 + kt * 64 + c * 8);
            *(short8*)((char*)Bl + n * 128 + ((c ^ (n & 7)) << 4)) = v;
        }
        __syncthreads();
#pragma unroll
        for (int kk = 0; kk < 2; ++kk) {
            short8 af[4], bfr[4];
#pragma unroll
            for (int m = 0; m < 4; ++m) {
                int r = wm * 64 + m * 16 + l15;
                af[m] = *(const short8*)((const char*)Al + r * 128 + (((kk * 4 + grp) ^ (r & 7)) << 4));
            }
#pragma unroll
            for (int n = 0; n < 4; ++n) {
                int r = wn * 64 + n * 16 + l15;
                bfr[n] = *(const short8*)((const char*)Bl + r * 128 + (((kk * 4 + grp) ^ (r & 7)) << 4));
            }
#pragma unroll
            for (int m = 0; m < 4; ++m)
#pragma unroll
                for (int n = 0; n < 4; ++n)
                    acc[m][n] = MFMA16(af[m], bfr[n], acc[m][n]);
        }
        __syncthreads();
    }
#pragma unroll
    for (int n = 0; n < 4; ++n) {
        int col = colbase + wn * 64 + n * 16 + l15;
        float bvv = bias[col];
#pragma unroll
        for (int m = 0; m < 4; ++m) {
            int row0 = rowbase + wm * 64 + m * 16 + grp * 4;
#pragma unroll
            for (int r = 0; r < 4; ++r)
                out[(size_t)(row0 + r) * 512 + col] = f2bf(acc[m][n][r] + bvv);
        }
    }
}

// ---------------------------------------------------------------------------
// Kernel 3: v (b,key,h*64+d) bf16 -> vT (b,h,d,key) bf16
// ---------------------------------------------------------------------------
__global__ __launch_bounds__(256) void vtrans_kernel(
    const unsigned short* __restrict__ vb, unsigned short* __restrict__ vT)
{
    __shared__ unsigned short tile[64][72];
    const int key0 = blockIdx.x * 64;
    const int h = blockIdx.y;
    const int b = blockIdx.z;
    const int t = threadIdx.x;

#pragma unroll
    for (int p = 0; p < 2; ++p) {
        int idx = p * 256 + t;
        int key = idx >> 3, c = idx & 7;
        short8 v = *(const short8*)(vb + (size_t)(b * 1024 + key0 + key) * 512 + h * 64 + c * 8);
        *(short8*)&tile[key][c * 8] = v;
    }
    __syncthreads();
#pragma unroll
    for (int p = 0; p < 2; ++p) {
        int idx = p * 256 + t;
        int d = idx >> 3, c = idx & 7;
        short8 o;
#pragma unroll
        for (int j = 0; j < 8; ++j) o[j] = (short)tile[c * 8 + j][d];
        *(short8*)(vT + ((size_t)(b * 8 + h) * 64 + d) * 1024 + key0 + c * 8) = o;
    }
}

// ---------------------------------------------------------------------------
// Kernel 4: flash attention, swapped-operand form. Block = 128 q rows (4 waves
// x 32 q), KVBLK=64. S^T = mfma(K, Q) so each lane owns 16 keys of ONE q col:
// softmax max = in-register + 2 shfl; P packed via cvt_pk -> [q][key] LDS;
// PV computed transposed: O^T = mfma(V^T, P^T). Epilogue adds residual q.
// ---------------------------------------------------------------------------
__global__ __launch_bounds__(256, 4) void attn_kernel(
    const unsigned short* __restrict__ qb, const unsigned short* __restrict__ kb,
    const unsigned short* __restrict__ vT, unsigned short* __restrict__ Opre)
{
    const int qt = blockIdx.x;  // 8 tiles of 128 q
    const int h  = blockIdx.y;  // 8
    const int b  = blockIdx.z;  // 16
    const int t = threadIdx.x, lane = t & 63, wid = t >> 6;
    const int l15 = lane & 15, grp = lane >> 4;
    const int qbase = qt * 128 + wid * 32;

    __shared__ unsigned short Kl[64 * 64];   // [key][kd] swizzled
    __shared__ unsigned short Vl[64 * 64];   // [d][key] swizzled
    __shared__ unsigned short Pl[4][32 * 64]; // per-wave [q=32][key=64] swizzled

    // Q as B-frags: qfrag[qf][kk] lane holds Q[qbase+qf*16+l15][h*64+kk*32+grp*8+j]
    short8 qfrag[2][2];
#pragma unroll
    for (int qf = 0; qf < 2; ++qf)
#pragma unroll
        for (int kk = 0; kk < 2; ++kk)
            qfrag[qf][kk] = *(const short8*)(
                qb + (size_t)(b * 1024 + qbase + qf * 16 + l15) * 512 + h * 64 + kk * 32 + grp * 8);

    f32x4 o[2][4];
#pragma unroll
    for (int qf = 0; qf < 2; ++qf)
#pragma unroll
        for (int df = 0; df < 4; ++df) o[qf][df] = (f32x4){0.f, 0.f, 0.f, 0.f};
    float mrun[2] = {-1e30f, -1e30f}, lrun[2] = {0.f, 0.f};

    const float C = 0.06375871f;  // (1/sqrt(512)) * log2(e)

    for (int kt = 0; kt < 16; ++kt) {
        // stage K tile [64 keys][64 kd] and V^T tile [64 d][64 keys], swizzled
#pragma unroll
        for (int p = 0; p < 2; ++p) {
            int idx = p * 256 + t;
            int key = idx >> 3, c = idx & 7;
            short8 v = *(const short8*)(kb + (size_t)(b * 1024 + kt * 64 + key) * 512 + h * 64 + c * 8);
            *(short8*)((char*)Kl + key * 128 + ((c ^ (key & 7)) << 4)) = v;
        }
#pragma unroll
        for (int p = 0; p < 2; ++p) {
            int idx = p * 256 + t;
            int d = idx >> 3, c = idx & 7;
            short8 v = *(const short8*)(vT + ((size_t)(b * 8 + h) * 64 + d) * 1024 + kt * 64 + c * 8);
            *(short8*)((char*)Vl + d * 128 + ((c ^ (d & 7)) << 4)) = v;
        }
        __syncthreads();

        // S^T = K . Q^T : s[qf][nf][r] = S[key = nf*16+grp*4+r][q = l15]
        f32x4 s[2][4];
#pragma unroll
        for (int qf = 0; qf < 2; ++qf)
#pragma unroll
            for (int nf = 0; nf < 4; ++nf) s[qf][nf] = (f32x4){0.f, 0.f, 0.f, 0.f};
#pragma unroll
        for (int kk = 0; kk < 2; ++kk) {
            short8 kf[4];
#pragma unroll
            for (int nf = 0; nf < 4; ++nf) {
                int r = nf * 16 + l15;
                kf[nf] = *(const short8*)((const char*)Kl + r * 128 + (((kk * 4 + grp) ^ (r & 7)) << 4));
            }
#pragma unroll
            for (int qf = 0; qf < 2; ++qf)
#pragma unroll
                for (int nf = 0; nf < 4; ++nf)
                    s[qf][nf] = MFMA16(kf[nf], qfrag[qf][kk], s[qf][nf]);
        }

        // online softmax per qf (scale folded into exp2 arg; max scale-invariant)
#pragma unroll
        for (int qf = 0; qf < 2; ++qf) {
            float m = s[qf][0][0];
#pragma unroll
            for (int nf = 0; nf < 4; ++nf)
#pragma unroll
                for (int r = 0; r < 4; ++r) m = fmaxf(m, s[qf][nf][r]);
            m = fmaxf(m, __shfl_xor(m, 16));
            m = fmaxf(m, __shfl_xor(m, 32));
            float mnew = fmaxf(mrun[qf], m);
            float rs = __builtin_amdgcn_exp2f((mrun[qf] - mnew) * C);
            mrun[qf] = mnew;
            lrun[qf] *= rs;
#pragma unroll
            for (int df = 0; df < 4; ++df)
#pragma unroll
                for (int r = 0; r < 4; ++r) o[qf][df][r] *= rs;

            // P = exp2((s - mnew)*C), pack pairs, write [q][key] swizzled
            int prow = qf * 16 + l15;
#pragma unroll
            for (int nf = 0; nf < 4; ++nf) {
                float p0 = __builtin_amdgcn_exp2f((s[qf][nf][0] - mnew) * C);
                float p1 = __builtin_amdgcn_exp2f((s[qf][nf][1] - mnew) * C);
                float p2 = __builtin_amdgcn_exp2f((s[qf][nf][2] - mnew) * C);
                float p3 = __builtin_amdgcn_exp2f((s[qf][nf][3] - mnew) * C);
                lrun[qf] += (p0 + p1) + (p2 + p3);
                uint2v w;
                w[0] = cvt_pk_bf16(p0, p1);
                w[1] = cvt_pk_bf16(p2, p3);
                // bytes: row prow, col (nf*16+grp*4)*2 -> block 2nf+(grp>>1), half (grp&1)
                unsigned addr = prow * 128 + (((2 * nf + (grp >> 1)) ^ (l15 & 7)) << 4) + (grp & 1) * 8;
                *(uint2v*)((char*)Pl[wid] + addr) = w;
            }
        }

        // PV transposed: o[qf][df] (= O^T[d][q]) += V^T-frag . P^T-frag
#pragma unroll
        for (int kk = 0; kk < 2; ++kk) {
            short8 pb[2];
#pragma unroll
            for (int qf = 0; qf < 2; ++qf) {
                int prow = qf * 16 + l15;
                pb[qf] = *(const short8*)((const char*)Pl[wid] + prow * 128 + (((kk * 4 + grp) ^ (l15 & 7)) << 4));
            }
#pragma unroll
            for (int df = 0; df < 4; ++df) {
                int r = df * 16 + l15;
                short8 vf = *(const short8*)((const char*)Vl + r * 128 + (((kk * 4 + grp) ^ (r & 7)) << 4));
#pragma unroll
                for (int qf = 0; qf < 2; ++qf)
                    o[qf][df] = MFMA16(vf, pb[qf], o[qf][df]);
            }
        }
        __syncthreads();
    }

    // epilogue: l-reduce across grp groups, normalize, add residual q, store
#pragma unroll
    for (int qf = 0; qf < 2; ++qf) {
        float l = lrun[qf];
        l += __shfl_xor(l, 16);
        l += __shfl_xor(l, 32);
        float linv = 1.f / l;
        size_t row = (size_t)(b * 1024 + qbase + qf * 16 + l15);
#pragma unroll
        for (int df = 0; df < 4; ++df) {
            int col = h * 64 + df * 16 + grp * 4;
            ushort4v res = *(const ushort4v*)(qb + row * 512 + col);
            ushort4v outv;
#pragma unroll
            for (int r = 0; r < 4; ++r)
                outv[r] = f2bf(o[qf][df][r] * linv + bf2f(res[r]));
            *(ushort4v*)(Opre + row * 512 + col) = outv;
        }
    }
}

// ---------------------------------------------------------------------------
// Kernel 5/7: LayerNorm over rows of 512. One wave per row.
// ---------------------------------------------------------------------------
template <int OUT_F32>
__global__ __launch_bounds__(256) void ln_kernel(
    const unsigned short* in, const float* __restrict__ g, const float* __restrict__ be,
    unsigned short* outb, float* outf)
{
    const int wid = threadIdx.x >> 6, lane = threadIdx.x & 63;
    const size_t row = (size_t)blockIdx.x * 4 + wid;
    short8 v = *(const short8*)(in + row * 512 + lane * 8);
    float x[8];
    float sum = 0.f, sq = 0.f;
#pragma unroll
    for (int j = 0; j < 8; ++j) {
        x[j] = bf2f((unsigned short)v[j]);
        sum += x[j];
        sq += x[j] * x[j];
    }
#pragma unroll
    for (int ofs = 1; ofs < 64; ofs <<= 1) {
        sum += __shfl_xor(sum, ofs);
        sq += __shfl_xor(sq, ofs);
    }
    float mean = sum * (1.f / 512.f);
    float var = sq * (1.f / 512.f) - mean * mean;
    float rs = rsqrtf(var + 1e-5f);
    float4v g0 = *(const float4v*)(g + lane * 8);
    float4v g1 = *(const float4v*)(g + lane * 8 + 4);
    float4v b0 = *(const float4v*)(be + lane * 8);
    float4v b1 = *(const float4v*)(be + lane * 8 + 4);
    float y[8];
#pragma unroll
    for (int j = 0; j < 4; ++j) y[j] = (x[j] - mean) * rs * g0[j] + b0[j];
#pragma unroll
    for (int j = 0; j < 4; ++j) y[4 + j] = (x[4 + j] - mean) * rs * g1[j] + b1[j];
    if (OUT_F32) {
        float4v o0, o1;
#pragma unroll
        for (int j = 0; j < 4; ++j) { o0[j] = y[j]; o1[j] = y[4 + j]; }
        *(float4v*)(outf + row * 512 + lane * 8) = o0;
        *(float4v*)(outf + row * 512 + lane * 8 + 4) = o1;
    } else {
        short8 o;
#pragma unroll
        for (int j = 0; j < 8; ++j) o[j] = (short)f2bf(y[j]);
        *(short8*)(outb + row * 512 + lane * 8) = o;
    }
}

// ---------------------------------------------------------------------------
// Kernel 6: O2 = O1 + relu(O1 @ Wo + bo)
// ---------------------------------------------------------------------------
__global__ __launch_bounds__(256) void ffn_kernel(
    const unsigned short* __restrict__ O1, const unsigned short* __restrict__ WoT,
    const float* __restrict__ bo, unsigned short* __restrict__ O2)
{
    __shared__ unsigned short Al[128 * 64];
    __shared__ unsigned short Bl[128 * 64];

    const int t = threadIdx.x;
    const int lane = t & 63, wid = t >> 6;
    const int wm = wid >> 1, wn = wid & 1;
    const int l15 = lane & 15, grp = lane >> 4;
    const int rowbase = blockIdx.y * 128;
    const int colbase = blockIdx.x * 128;

    f32x4 acc[4][4];
#pragma unroll
    for (int i = 0; i < 4; ++i)
#pragma unroll
        for (int j = 0; j < 4; ++j) acc[i][j] = (f32x4){0.f, 0.f, 0.f, 0.f};

    for (int kt = 0; kt < 8; ++kt) {
#pragma unroll
        for (int p = 0; p < 4; ++p) {
            int idx = p * 256 + t;
            int r = idx >> 3, c = idx & 7;
            short8 v = *(const short8*)(O1 + (size_t)(rowbase + r) * 512 + kt * 64 + c * 8);
            *(short8*)((char*)Al + r * 128 + ((c ^ (r & 7)) << 4)) = v;
        }
#pragma unroll
        for (int p = 0; p < 4; ++p) {
            int idx = p * 256 + t;
            int n = idx >> 3, c = idx & 7;
            short8 v = *(const short8*)(WoT + (size_t)(colbase + n) * 512 + kt * 64 + c * 8);
            *(short8*)((char*)Bl + n * 128 + ((c ^ (n & 7)) << 4)) = v;
        }
        __syncthreads();
#pragma unroll
        for (int kk = 0; kk < 2; ++kk) {
            short8 af[4], bfr[4];
#pragma unroll
            for (int m = 0; m < 4; ++m) {
                int r = wm * 64 + m * 16 + l15;
                af[m] = *(const short8*)((const char*)Al + r * 128 + (((kk * 4 + grp) ^ (r & 7)) << 4));
            }
#pragma unroll
            for (int n = 0; n < 4; ++n) {
                int r = wn * 64 + n * 16 + l15;
                bfr[n] = *(const short8*)((const char*)Bl + r * 128 + (((kk * 4 + grp) ^ (r & 7)) << 4));
            }
#pragma unroll
            for (int m = 0; m < 4; ++m)
#pragma unroll
                for (int n = 0; n < 4; ++n)
                    acc[m][n] = MFMA16(af[m], bfr[n], acc[m][n]);
        }
        __syncthreads();
    }
#pragma unroll
    for (int n = 0; n < 4; ++n) {
        int col = colbase + wn * 64 + n * 16 + l15;
        float bvv = bo[col];
#pragma unroll
        for (int m = 0; m < 4; ++m) {
            int row0 = rowbase + wm * 64 + m * 16 + grp * 4;
#pragma unroll
            for (int r = 0; r < 4; ++r) {
                size_t row = (size_t)(row0 + r);
                float val = fmaxf(acc[m][n][r] + bvv, 0.f);
                float resid = bf2f(O1[row * 512 + col]);
                O2[row * 512 + col] = f2bf(resid + val);
            }
        }
    }
}

// ---------------------------------------------------------------------------
extern "C" void kernel_launch(void* const* d_in, const int* in_sizes, int n_in,
                              void* d_out, int out_size, void* d_ws, size_t ws_size,
                              hipStream_t stream)
{
    const float* Q   = (const float*)d_in[0];
    const float* Kin = (const float*)d_in[1];
    const float* Wq  = (const float*)d_in[2];
    const float* bq  = (const float*)d_in[3];
    const float* Wk  = (const float*)d_in[4];
    const float* bk  = (const float*)d_in[5];
    const float* Wv  = (const float*)d_in[6];
    const float* bv  = (const float*)d_in[7];
    const float* Wo  = (const float*)d_in[8];
    const float* bo  = (const float*)d_in[9];
    const float* g0  = (const float*)d_in[10];
    const float* b0  = (const float*)d_in[11];
    const float* g1  = (const float*)d_in[12];
    const float* b1  = (const float*)d_in[13];
    float* out = (float*)d_out;

    unsigned short* ws = (unsigned short*)d_ws;
    const size_t WSZ = 512 * 512;
    const size_t BIG = 16384 * 512;
    unsigned short* WqT  = ws;
    unsigned short* WkT  = WqT + WSZ;
    unsigned short* WvT  = WkT + WSZ;
    unsigned short* WoT  = WvT + WSZ;
    unsigned short* qb   = WoT + WSZ;
    unsigned short* kb   = qb + BIG;
    unsigned short* vb   = kb + BIG;
    unsigned short* vT   = vb + BIG;
    unsigned short* Opre = vT + BIG;
    unsigned short* Qbf  = Opre + BIG;
    unsigned short* Kbf  = Qbf + BIG;
    unsigned short* O1   = Opre;   // LN0 in place
    unsigned short* O2   = vb;     // vb dead after vtrans

    cvt_kernel<<<dim3(4096, 1, 2), 256, 0, stream>>>(Q, Kin, Qbf, Kbf);
    wtrans_kernel<<<dim3(8, 8, 4), 256, 0, stream>>>(Wq, Wk, Wv, Wo, WqT, WkT, WvT, WoT);
    proj_kernel<<<dim3(4, 128, 3), 256, 0, stream>>>(Qbf, Kbf, WqT, WkT, WvT, bq, bk, bv, qb, kb, vb);
    vtrans_kernel<<<dim3(16, 8, 16), 256, 0, stream>>>(vb, vT);
    attn_kernel<<<dim3(8, 8, 16), 256, 0, stream>>>(qb, kb, vT, Opre);
    ln_kernel<0><<<dim3(4096), 256, 0, stream>>>(Opre, g0, b0, O1, nullptr);
    ffn_kernel<<<dim3(4, 128), 256, 0, stream>>>(O1, WoT, bo, O2);
    ln_kernel<1><<<dim3(4096), 256, 0, stream>>>(O2, g1, b1, nullptr, out);
}

// Round 3
// 168.786 us; speedup vs baseline: 1.2565x; 1.0168x over previous
//
#include <hip/hip_runtime.h>
#include <hip/hip_bf16.h>

typedef __attribute__((ext_vector_type(8))) short short8;
typedef __attribute__((ext_vector_type(4))) float f32x4;
typedef __attribute__((ext_vector_type(4))) float float4v;
typedef __attribute__((ext_vector_type(4))) unsigned short ushort4v;
typedef __attribute__((ext_vector_type(2))) unsigned int uint2v;

#define MFMA16(a, b, c) __builtin_amdgcn_mfma_f32_16x16x32_bf16((a), (b), (c), 0, 0, 0)

__device__ __forceinline__ unsigned short f2bf(float f) {
    union { float f; unsigned u; } v; v.f = f;
    unsigned r = v.u + 0x7fffu + ((v.u >> 16) & 1u);
    return (unsigned short)(r >> 16);
}
__device__ __forceinline__ float bf2f(unsigned short h) {
    union { unsigned u; float f; } v; v.u = (unsigned)h << 16;
    return v.f;
}
__device__ __forceinline__ unsigned cvt_pk_bf16(float lo, float hi) {
    unsigned r;
    asm("v_cvt_pk_bf16_f32 %0, %1, %2" : "=v"(r) : "v"(lo), "v"(hi));
    return r;
}
// async global->LDS, 16B per lane. LDS dest = wave-uniform base + lane*16.
__device__ __forceinline__ void gl16(const void* g, void* l) {
    __builtin_amdgcn_global_load_lds(
        (const __attribute__((address_space(1))) unsigned int*)g,
        (__attribute__((address_space(3))) unsigned int*)l, 16, 0, 0);
}

// ---------------------------------------------------------------------------
// Kernel 0: fp32 -> bf16 convert Q,K. Output PRE-SWIZZLED: within each 64-col
// block, 8-short chunk c stored at c ^ (row&7)  (so GEMM gload_lds is linear).
// ---------------------------------------------------------------------------
__global__ __launch_bounds__(256) void cvt_kernel(
    const float* __restrict__ Q, const float* __restrict__ K,
    unsigned short* __restrict__ Qb, unsigned short* __restrict__ Kb)
{
    const float* in = blockIdx.z ? K : Q;
    unsigned short* out = blockIdx.z ? Kb : Qb;
    size_t i = ((size_t)blockIdx.x * 256 + threadIdx.x) * 8;
    float4v v0 = *(const float4v*)(in + i);
    float4v v1 = *(const float4v*)(in + i + 4);
    short8 o;
#pragma unroll
    for (int j = 0; j < 4; ++j) { o[j] = (short)f2bf(v0[j]); o[4 + j] = (short)f2bf(v1[j]); }
    size_t row7 = (i >> 9) & 7;
    *(short8*)(out + (i ^ (row7 << 3))) = o;
}

// ---------------------------------------------------------------------------
// Kernel 1: weights 512x512 fp32 -> bf16 transposed, PRE-SWIZZLED rows.
// ---------------------------------------------------------------------------
__global__ __launch_bounds__(256) void wtrans_kernel(
    const float* __restrict__ W0, const float* __restrict__ W1,
    const float* __restrict__ W2, const float* __restrict__ W3,
    unsigned short* __restrict__ T0, unsigned short* __restrict__ T1,
    unsigned short* __restrict__ T2, unsigned short* __restrict__ T3)
{
    const int z = blockIdx.z;
    const float* W = (z == 0) ? W0 : (z == 1) ? W1 : (z == 2) ? W2 : W3;
    unsigned short* T = (z == 0) ? T0 : (z == 1) ? T1 : (z == 2) ? T2 : T3;

    __shared__ unsigned short tile[64][72];
    const int k0 = blockIdx.x * 64, n0 = blockIdx.y * 64;
    const int t = threadIdx.x;

#pragma unroll
    for (int p = 0; p < 4; ++p) {
        int idx = p * 256 + t;
        int k = idx >> 4, c4 = idx & 15;
        float4v v = *(const float4v*)(W + (size_t)(k0 + k) * 512 + n0 + c4 * 4);
#pragma unroll
        for (int j = 0; j < 4; ++j) tile[k][c4 * 4 + j] = f2bf(v[j]);
    }
    __syncthreads();
#pragma unroll
    for (int p = 0; p < 2; ++p) {
        int idx = p * 256 + t;
        int n = idx >> 3, c = idx & 7;
        short8 o;
#pragma unroll
        for (int j = 0; j < 8; ++j) o[j] = (short)tile[c * 8 + j][n];
        *(short8*)(T + (size_t)(n0 + n) * 512 + k0 + ((c ^ (n & 7)) * 8)) = o;
    }
}

// ---------------------------------------------------------------------------
// Kernel 2: q/k/v projection GEMM. A,B staged via global_load_lds (sources
// pre-swizzled => LDS content identical to explicit-swizzle version).
// z==1 (k) epilogue writes kb PRE-SWIZZLED for attn's K staging.
// ---------------------------------------------------------------------------
__global__ __launch_bounds__(256) void proj_kernel(
    const unsigned short* __restrict__ Qb, const unsigned short* __restrict__ Kb,
    const unsigned short* __restrict__ WqT, const unsigned short* __restrict__ WkT,
    const unsigned short* __restrict__ WvT,
    const float* __restrict__ bq, const float* __restrict__ bk, const float* __restrict__ bv,
    unsigned short* __restrict__ qb, unsigned short* __restrict__ kb,
    unsigned short* __restrict__ vb)
{
    const int z = blockIdx.z;
    const unsigned short* A = (z == 0) ? Qb : Kb;
    const unsigned short* WT = (z == 0) ? WqT : (z == 1) ? WkT : WvT;
    const float* bias = (z == 0) ? bq : (z == 1) ? bk : bv;
    unsigned short* out = (z == 0) ? qb : (z == 1) ? kb : vb;

    __shared__ unsigned short Al[128 * 64];
    __shared__ unsigned short Bl[128 * 64];

    const int t = threadIdx.x;
    const int lane = t & 63, wid = t >> 6;
    const int wm = wid >> 1, wn = wid & 1;
    const int l15 = lane & 15, grp = lane >> 4;
    const int rowbase = blockIdx.y * 128;
    const int colbase = blockIdx.x * 128;
    const int srow = t >> 3, sblk = t & 7;

    f32x4 acc[4][4];
#pragma unroll
    for (int i = 0; i < 4; ++i)
#pragma unroll
        for (int j = 0; j < 4; ++j) acc[i][j] = (f32x4){0.f, 0.f, 0.f, 0.f};

    for (int kt = 0; kt < 8; ++kt) {
#pragma unroll
        for (int p = 0; p < 4; ++p)
            gl16(A + (size_t)(rowbase + p * 32 + srow) * 512 + kt * 64 + sblk * 8,
                 &Al[p * 2048 + wid * 512]);
#pragma unroll
        for (int p = 0; p < 4; ++p)
            gl16(WT + (size_t)(colbase + p * 32 + srow) * 512 + kt * 64 + sblk * 8,
                 &Bl[p * 2048 + wid * 512]);
        __syncthreads();
#pragma unroll
        for (int kk = 0; kk < 2; ++kk) {
            short8 af[4], bfr[4];
#pragma unroll
            for (int m = 0; m < 4; ++m) {
                int r = wm * 64 + m * 16 + l15;
                af[m] = *(const short8*)((const char*)Al + r * 128 + (((kk * 4 + grp) ^ (r & 7)) << 4));
            }
#pragma unroll
            for (int n = 0; n < 4; ++n) {
                int r = wn * 64 + n * 16 + l15;
                bfr[n] = *(const short8*)((const char*)Bl + r * 128 + (((kk * 4 + grp) ^ (r & 7)) << 4));
            }
#pragma unroll
            for (int m = 0; m < 4; ++m)
#pragma unroll
                for (int n = 0; n < 4; ++n)
                    acc[m][n] = MFMA16(af[m], bfr[n], acc[m][n]);
        }
        __syncthreads();
    }
#pragma unroll
    for (int n = 0; n < 4; ++n) {
        int col = colbase + wn * 64 + n * 16 + l15;
        float bvv = bias[col];
#pragma unroll
        for (int m = 0; m < 4; ++m) {
            int row0 = rowbase + wm * 64 + m * 16 + grp * 4;
#pragma unroll
            for (int r = 0; r < 4; ++r) {
                int row = row0 + r;
                int colp = (z == 1) ? (col ^ ((row & 7) << 3)) : col;
                out[(size_t)row * 512 + colp] = f2bf(acc[m][n][r] + bvv);
            }
        }
    }
}

// ---------------------------------------------------------------------------
// Kernel 3: v -> vT (b,h,d,key), PRE-SWIZZLED key-blocks for attn V staging.
// ---------------------------------------------------------------------------
__global__ __launch_bounds__(256) void vtrans_kernel(
    const unsigned short* __restrict__ vb, unsigned short* __restrict__ vT)
{
    __shared__ unsigned short tile[64][72];
    const int key0 = blockIdx.x * 64;
    const int h = blockIdx.y;
    const int b = blockIdx.z;
    const int t = threadIdx.x;

#pragma unroll
    for (int p = 0; p < 2; ++p) {
        int idx = p * 256 + t;
        int key = idx >> 3, c = idx & 7;
        short8 v = *(const short8*)(vb + (size_t)(b * 1024 + key0 + key) * 512 + h * 64 + c * 8);
        *(short8*)&tile[key][c * 8] = v;
    }
    __syncthreads();
#pragma unroll
    for (int p = 0; p < 2; ++p) {
        int idx = p * 256 + t;
        int dd = idx >> 3, c = idx & 7;
        short8 o;
#pragma unroll
        for (int j = 0; j < 8; ++j) o[j] = (short)tile[c * 8 + j][dd];
        *(short8*)(vT + ((size_t)(b * 8 + h) * 64 + dd) * 1024 + key0 + ((c ^ (dd & 7)) * 8)) = o;
    }
}

// ---------------------------------------------------------------------------
// Kernel 4: flash attention. 512 threads = 8 waves x 32 q; grid 512 (2/CU),
// XCD-aware decode (h = xcd). K/V double-buffered via global_load_lds from
// pre-swizzled kb/vT. Swapped-operand QK^T; defer-max; P via cvt_pk -> LDS.
// ---------------------------------------------------------------------------
__global__ __launch_bounds__(512, 4) void attn_kernel(
    const unsigned short* __restrict__ qb, const unsigned short* __restrict__ kbs,
    const unsigned short* __restrict__ vTs, unsigned short* __restrict__ Opre)
{
    __shared__ unsigned short Kl[2][64 * 64];
    __shared__ unsigned short Vl[2][64 * 64];
    __shared__ unsigned short Pl[8][32 * 64];

    const int t = threadIdx.x, lane = t & 63, wid = t >> 6;
    const int l15 = lane & 15, grp = lane >> 4;

    // XCD-aware decode: all 64 wgs on an XCD share h; (h,b) siblings adjacent.
    const int dd = blockIdx.x;           // 0..511
    const int xcd = dd & 7, rr = dd >> 3;
    const int h = xcd, b = rr >> 2, qt = rr & 3;
    const int qbase = qt * 256 + wid * 32;

    // staging source addrs (per-lane); dest = wave-uniform base + lane*16
    const int skey = t >> 3, sblk = t & 7;
    const unsigned short* kbase = kbs + (size_t)(b * 1024 + skey) * 512 + h * 64 + sblk * 8;
    const unsigned short* vbase = vTs + ((size_t)(b * 8 + h) * 64 + skey) * 1024 + sblk * 8;

#define STAGE(bsel, tile) do { \
    gl16(kbase + (size_t)(tile) * 32768, &Kl[bsel][wid * 512]); \
    gl16(vbase + (tile) * 64, &Vl[bsel][wid * 512]); } while (0)

    // Q as B-frags
    short8 qfrag[2][2];
#pragma unroll
    for (int qf = 0; qf < 2; ++qf)
#pragma unroll
        for (int kk = 0; kk < 2; ++kk)
            qfrag[qf][kk] = *(const short8*)(
                qb + (size_t)(b * 1024 + qbase + qf * 16 + l15) * 512 + h * 64 + kk * 32 + grp * 8);

    f32x4 o[2][4];
#pragma unroll
    for (int qf = 0; qf < 2; ++qf)
#pragma unroll
        for (int df = 0; df < 4; ++df) o[qf][df] = (f32x4){0.f, 0.f, 0.f, 0.f};
    float mrun[2] = {-1e30f, -1e30f}, lrun[2] = {0.f, 0.f};

    const float C = 0.06375871f;  // (1/sqrt(512)) * log2(e)

    STAGE(0, 0);
    __syncthreads();
    int buf = 0;

    for (int kt = 0; kt < 16; ++kt) {
        if (kt < 15) STAGE(buf ^ 1, kt + 1);   // flies during compute

        const char* Kb_ = (const char*)&Kl[buf][0];
        const char* Vb_ = (const char*)&Vl[buf][0];

        // S^T = K . Q^T : s[qf][nf][r] = S[key=nf*16+grp*4+r][q=l15]
        f32x4 s[2][4];
#pragma unroll
        for (int qf = 0; qf < 2; ++qf)
#pragma unroll
            for (int nf = 0; nf < 4; ++nf) s[qf][nf] = (f32x4){0.f, 0.f, 0.f, 0.f};
#pragma unroll
        for (int kk = 0; kk < 2; ++kk) {
            short8 kf[4];
#pragma unroll
            for (int nf = 0; nf < 4; ++nf) {
                int r = nf * 16 + l15;
                kf[nf] = *(const short8*)(Kb_ + r * 128 + (((kk * 4 + grp) ^ (r & 7)) << 4));
            }
#pragma unroll
            for (int qf = 0; qf < 2; ++qf)
#pragma unroll
                for (int nf = 0; nf < 4; ++nf)
                    s[qf][nf] = MFMA16(kf[nf], qfrag[qf][kk], s[qf][nf]);
        }

#pragma unroll
        for (int qf = 0; qf < 2; ++qf) {
            // balanced max tree (16 -> 1), then cross-grp
            float a0 = fmaxf(fmaxf(s[qf][0][0], s[qf][0][1]), fmaxf(s[qf][0][2], s[qf][0][3]));
            float a1 = fmaxf(fmaxf(s[qf][1][0], s[qf][1][1]), fmaxf(s[qf][1][2], s[qf][1][3]));
            float a2 = fmaxf(fmaxf(s[qf][2][0], s[qf][2][1]), fmaxf(s[qf][2][2], s[qf][2][3]));
            float a3 = fmaxf(fmaxf(s[qf][3][0], s[qf][3][1]), fmaxf(s[qf][3][2], s[qf][3][3]));
            float m = fmaxf(fmaxf(a0, a1), fmaxf(a2, a3));
            m = fmaxf(m, __shfl_xor(m, 16));
            m = fmaxf(m, __shfl_xor(m, 32));
            // defer-max: only rescale when tile max grew by > 8 (in exp2 units)
            if (__any((m - mrun[qf]) * C > 8.f)) {
                float mnew = fmaxf(mrun[qf], m);
                float rs = __builtin_amdgcn_exp2f((mrun[qf] - mnew) * C);
                mrun[qf] = mnew;
                lrun[qf] *= rs;
#pragma unroll
                for (int df = 0; df < 4; ++df)
#pragma unroll
                    for (int r = 0; r < 4; ++r) o[qf][df][r] *= rs;
            }

            int prow = qf * 16 + l15;
#pragma unroll
            for (int nf = 0; nf < 4; ++nf) {
                float p0 = __builtin_amdgcn_exp2f((s[qf][nf][0] - mrun[qf]) * C);
                float p1 = __builtin_amdgcn_exp2f((s[qf][nf][1] - mrun[qf]) * C);
                float p2 = __builtin_amdgcn_exp2f((s[qf][nf][2] - mrun[qf]) * C);
                float p3 = __builtin_amdgcn_exp2f((s[qf][nf][3] - mrun[qf]) * C);
                lrun[qf] += (p0 + p1) + (p2 + p3);
                uint2v w;
                w[0] = cvt_pk_bf16(p0, p1);
                w[1] = cvt_pk_bf16(p2, p3);
                unsigned addr = prow * 128 + (((2 * nf + (grp >> 1)) ^ (l15 & 7)) << 4) + (grp & 1) * 8;
                *(uint2v*)((char*)Pl[wid] + addr) = w;
            }
        }

        // PV transposed: o[qf][df] (= O^T[d][q]) += V^T-frag . P^T-frag
#pragma unroll
        for (int kk = 0; kk < 2; ++kk) {
            short8 pb[2];
#pragma unroll
            for (int qf = 0; qf < 2; ++qf) {
                int prow = qf * 16 + l15;
                pb[qf] = *(const short8*)((const char*)Pl[wid] + prow * 128 + (((kk * 4 + grp) ^ (l15 & 7)) << 4));
            }
#pragma unroll
            for (int df = 0; df < 4; ++df) {
                int r = df * 16 + l15;
                short8 vf = *(const short8*)(Vb_ + r * 128 + (((kk * 4 + grp) ^ (r & 7)) << 4));
#pragma unroll
                for (int qf = 0; qf < 2; ++qf)
                    o[qf][df] = MFMA16(vf, pb[qf], o[qf][df]);
            }
        }
        __syncthreads();
        buf ^= 1;
    }
#undef STAGE

#pragma unroll
    for (int qf = 0; qf < 2; ++qf) {
        float l = lrun[qf];
        l += __shfl_xor(l, 16);
        l += __shfl_xor(l, 32);
        float linv = 1.f / l;
        size_t row = (size_t)(b * 1024 + qbase + qf * 16 + l15);
#pragma unroll
        for (int df = 0; df < 4; ++df) {
            int col = h * 64 + df * 16 + grp * 4;
            ushort4v res = *(const ushort4v*)(qb + row * 512 + col);
            ushort4v outv;
#pragma unroll
            for (int r = 0; r < 4; ++r)
                outv[r] = f2bf(o[qf][df][r] * linv + bf2f(res[r]));
            *(ushort4v*)(Opre + row * 512 + col) = outv;
        }
    }
}

// ---------------------------------------------------------------------------
// Kernel 5/7: LayerNorm. OUT_F32=0 writes bf16 PRE-SWIZZLED (for ffn staging);
// OUT_F32=1 writes fp32 final output.
// ---------------------------------------------------------------------------
template <int OUT_F32>
__global__ __launch_bounds__(256) void ln_kernel(
    const unsigned short* in, const float* __restrict__ g, const float* __restrict__ be,
    unsigned short* outb, float* outf)
{
    const int wid = threadIdx.x >> 6, lane = threadIdx.x & 63;
    const size_t row = (size_t)blockIdx.x * 4 + wid;
    short8 v = *(const short8*)(in + row * 512 + lane * 8);
    float x[8];
    float sum = 0.f, sq = 0.f;
#pragma unroll
    for (int j = 0; j < 8; ++j) {
        x[j] = bf2f((unsigned short)v[j]);
        sum += x[j];
        sq += x[j] * x[j];
    }
#pragma unroll
    for (int ofs = 1; ofs < 64; ofs <<= 1) {
        sum += __shfl_xor(sum, ofs);
        sq += __shfl_xor(sq, ofs);
    }
    float mean = sum * (1.f / 512.f);
    float var = sq * (1.f / 512.f) - mean * mean;
    float rs = rsqrtf(var + 1e-5f);
    float4v g0 = *(const float4v*)(g + lane * 8);
    float4v g1 = *(const float4v*)(g + lane * 8 + 4);
    float4v b0 = *(const float4v*)(be + lane * 8);
    float4v b1 = *(const float4v*)(be + lane * 8 + 4);
    float y[8];
#pragma unroll
    for (int j = 0; j < 4; ++j) y[j] = (x[j] - mean) * rs * g0[j] + b0[j];
#pragma unroll
    for (int j = 0; j < 4; ++j) y[4 + j] = (x[4 + j] - mean) * rs * g1[j] + b1[j];
    if (OUT_F32) {
        float4v o0, o1;
#pragma unroll
        for (int j = 0; j < 4; ++j) { o0[j] = y[j]; o1[j] = y[4 + j]; }
        *(float4v*)(outf + row * 512 + lane * 8) = o0;
        *(float4v*)(outf + row * 512 + lane * 8 + 4) = o1;
    } else {
        short8 o;
#pragma unroll
        for (int j = 0; j < 8; ++j) o[j] = (short)f2bf(y[j]);
        size_t op = row * 512 + (size_t)((lane >> 3) * 64 + (((lane & 7) ^ ((int)row & 7)) * 8));
        *(short8*)(outb + op) = o;
    }
}

// ---------------------------------------------------------------------------
// Kernel 6: O2 = O1 + relu(O1 @ Wo + bo). O1,WoT pre-swizzled; gload_lds stage.
// ---------------------------------------------------------------------------
__global__ __launch_bounds__(256) void ffn_kernel(
    const unsigned short* __restrict__ O1, const unsigned short* __restrict__ WoT,
    const float* __restrict__ bo, unsigned short* __restrict__ O2)
{
    __shared__ unsigned short Al[128 * 64];
    __shared__ unsigned short Bl[128 * 64];

    const int t = threadIdx.x;
    const int lane = t & 63, wid = t >> 6;
    const int wm = wid >> 1, wn = wid & 1;
    const int l15 = lane & 15, grp = lane >> 4;
    const int rowbase = blockIdx.y * 128;
    const int colbase = blockIdx.x * 128;
    const int srow = t >> 3, sblk = t & 7;

    f32x4 acc[4][4];
#pragma unroll
    for (int i = 0; i < 4; ++i)
#pragma unroll
        for (int j = 0; j < 4; ++j) acc[i][j] = (f32x4){0.f, 0.f, 0.f, 0.f};

    for (int kt = 0; kt < 8; ++kt) {
#pragma unroll
        for (int p = 0; p < 4; ++p)
            gl16(O1 + (size_t)(rowbase + p * 32 + srow) * 512 + kt * 64 + sblk * 8,
                 &Al[p * 2048 + wid * 512]);
#pragma unroll
        for (int p = 0; p < 4; ++p)
            gl16(WoT + (size_t)(colbase + p * 32 + srow) * 512 + kt * 64 + sblk * 8,
                 &Bl[p * 2048 + wid * 512]);
        __syncthreads();
#pragma unroll
        for (int kk = 0; kk < 2; ++kk) {
            short8 af[4], bfr[4];
#pragma unroll
            for (int m = 0; m < 4; ++m) {
                int r = wm * 64 + m * 16 + l15;
                af[m] = *(const short8*)((const char*)Al + r * 128 + (((kk * 4 + grp) ^ (r & 7)) << 4));
            }
#pragma unroll
            for (int n = 0; n < 4; ++n) {
                int r = wn * 64 + n * 16 + l15;
                bfr[n] = *(const short8*)((const char*)Bl + r * 128 + (((kk * 4 + grp) ^ (r & 7)) << 4));
            }
#pragma unroll
            for (int m = 0; m < 4; ++m)
#pragma unroll
                for (int n = 0; n < 4; ++n)
                    acc[m][n] = MFMA16(af[m], bfr[n], acc[m][n]);
        }
        __syncthreads();
    }
#pragma unroll
    for (int n = 0; n < 4; ++n) {
        int col = colbase + wn * 64 + n * 16 + l15;
        float bvv = bo[col];
#pragma unroll
        for (int m = 0; m < 4; ++m) {
            int row0 = rowbase + wm * 64 + m * 16 + grp * 4;
#pragma unroll
            for (int r = 0; r < 4; ++r) {
                size_t row = (size_t)(row0 + r);
                float val = fmaxf(acc[m][n][r] + bvv, 0.f);
                float resid = bf2f(O1[row * 512 + (col ^ (((int)row & 7) << 3))]);
                O2[row * 512 + col] = f2bf(resid + val);
            }
        }
    }
}

// ---------------------------------------------------------------------------
extern "C" void kernel_launch(void* const* d_in, const int* in_sizes, int n_in,
                              void* d_out, int out_size, void* d_ws, size_t ws_size,
                              hipStream_t stream)
{
    const float* Q   = (const float*)d_in[0];
    const float* Kin = (const float*)d_in[1];
    const float* Wq  = (const float*)d_in[2];
    const float* bq  = (const float*)d_in[3];
    const float* Wk  = (const float*)d_in[4];
    const float* bk  = (const float*)d_in[5];
    const float* Wv  = (const float*)d_in[6];
    const float* bv  = (const float*)d_in[7];
    const float* Wo  = (const float*)d_in[8];
    const float* bo  = (const float*)d_in[9];
    const float* g0  = (const float*)d_in[10];
    const float* b0  = (const float*)d_in[11];
    const float* g1  = (const float*)d_in[12];
    const float* b1  = (const float*)d_in[13];
    float* out = (float*)d_out;

    unsigned short* ws = (unsigned short*)d_ws;
    const size_t WSZ = 512 * 512;
    const size_t BIG = 16384 * 512;
    unsigned short* WqT  = ws;
    unsigned short* WkT  = WqT + WSZ;
    unsigned short* WvT  = WkT + WSZ;
    unsigned short* WoT  = WvT + WSZ;
    unsigned short* qb   = WoT + WSZ;
    unsigned short* kb   = qb + BIG;
    unsigned short* vb   = kb + BIG;
    unsigned short* vT   = vb + BIG;
    unsigned short* Opre = vT + BIG;
    unsigned short* Qbf  = Opre + BIG;
    unsigned short* Kbf  = Qbf + BIG;
    unsigned short* O1   = Opre;   // LN0 in place
    unsigned short* O2   = vb;     // vb dead after vtrans

    cvt_kernel<<<dim3(4096, 1, 2), 256, 0, stream>>>(Q, Kin, Qbf, Kbf);
    wtrans_kernel<<<dim3(8, 8, 4), 256, 0, stream>>>(Wq, Wk, Wv, Wo, WqT, WkT, WvT, WoT);
    proj_kernel<<<dim3(4, 128, 3), 256, 0, stream>>>(Qbf, Kbf, WqT, WkT, WvT, bq, bk, bv, qb, kb, vb);
    vtrans_kernel<<<dim3(16, 8, 16), 256, 0, stream>>>(vb, vT);
    attn_kernel<<<dim3(512), 512, 0, stream>>>(qb, kb, vT, Opre);
    ln_kernel<0><<<dim3(4096), 256, 0, stream>>>(Opre, g0, b0, O1, nullptr);
    ffn_kernel<<<dim3(4, 128), 256, 0, stream>>>(O1, WoT, bo, O2);
    ln_kernel<1><<<dim3(4096), 256, 0, stream>>>(O2, g1, b1, nullptr, out);
}

// Round 4
// 164.373 us; speedup vs baseline: 1.2903x; 1.0268x over previous
//
#include <hip/hip_runtime.h>
#include <hip/hip_bf16.h>

typedef __attribute__((ext_vector_type(8))) short short8;
typedef __attribute__((ext_vector_type(4))) float f32x4;
typedef __attribute__((ext_vector_type(4))) float float4v;
typedef __attribute__((ext_vector_type(4))) unsigned short ushort4v;
typedef __attribute__((ext_vector_type(2))) unsigned int uint2v;

#define MFMA16(a, b, c) __builtin_amdgcn_mfma_f32_16x16x32_bf16((a), (b), (c), 0, 0, 0)

__device__ __forceinline__ unsigned short f2bf(float f) {
    union { float f; unsigned u; } v; v.f = f;
    unsigned r = v.u + 0x7fffu + ((v.u >> 16) & 1u);
    return (unsigned short)(r >> 16);
}
__device__ __forceinline__ float bf2f(unsigned short h) {
    union { unsigned u; float f; } v; v.u = (unsigned)h << 16;
    return v.f;
}
__device__ __forceinline__ unsigned cvt_pk_bf16(float lo, float hi) {
    unsigned r;
    asm("v_cvt_pk_bf16_f32 %0, %1, %2" : "=v"(r) : "v"(lo), "v"(hi));
    return r;
}
// async global->LDS, 16B per lane. LDS dest = wave-uniform base + lane*16.
__device__ __forceinline__ void gl16(const void* g, void* l) {
    __builtin_amdgcn_global_load_lds(
        (const __attribute__((address_space(1))) unsigned int*)g,
        (__attribute__((address_space(3))) unsigned int*)l, 16, 0, 0);
}

// ---------------------------------------------------------------------------
// Kernel 0: fp32 -> bf16 convert Q,K. Output PRE-SWIZZLED: within each 64-col
// block, 8-short chunk c stored at c ^ (row&7)  (so GEMM gload_lds is linear).
// ---------------------------------------------------------------------------
__global__ __launch_bounds__(256) void cvt_kernel(
    const float* __restrict__ Q, const float* __restrict__ K,
    unsigned short* __restrict__ Qb, unsigned short* __restrict__ Kb)
{
    const float* in = blockIdx.z ? K : Q;
    unsigned short* out = blockIdx.z ? Kb : Qb;
    size_t i = ((size_t)blockIdx.x * 256 + threadIdx.x) * 8;
    float4v v0 = *(const float4v*)(in + i);
    float4v v1 = *(const float4v*)(in + i + 4);
    short8 o;
#pragma unroll
    for (int j = 0; j < 4; ++j) { o[j] = (short)f2bf(v0[j]); o[4 + j] = (short)f2bf(v1[j]); }
    size_t row7 = (i >> 9) & 7;
    *(short8*)(out + (i ^ (row7 << 3))) = o;
}

// ---------------------------------------------------------------------------
// Kernel 1: weights 512x512 fp32 -> bf16 transposed, PRE-SWIZZLED rows.
// ---------------------------------------------------------------------------
__global__ __launch_bounds__(256) void wtrans_kernel(
    const float* __restrict__ W0, const float* __restrict__ W1,
    const float* __restrict__ W2, const float* __restrict__ W3,
    unsigned short* __restrict__ T0, unsigned short* __restrict__ T1,
    unsigned short* __restrict__ T2, unsigned short* __restrict__ T3)
{
    const int z = blockIdx.z;
    const float* W = (z == 0) ? W0 : (z == 1) ? W1 : (z == 2) ? W2 : W3;
    unsigned short* T = (z == 0) ? T0 : (z == 1) ? T1 : (z == 2) ? T2 : T3;

    __shared__ unsigned short tile[64][72];
    const int k0 = blockIdx.x * 64, n0 = blockIdx.y * 64;
    const int t = threadIdx.x;

#pragma unroll
    for (int p = 0; p < 4; ++p) {
        int idx = p * 256 + t;
        int k = idx >> 4, c4 = idx & 15;
        float4v v = *(const float4v*)(W + (size_t)(k0 + k) * 512 + n0 + c4 * 4);
#pragma unroll
        for (int j = 0; j < 4; ++j) tile[k][c4 * 4 + j] = f2bf(v[j]);
    }
    __syncthreads();
#pragma unroll
    for (int p = 0; p < 2; ++p) {
        int idx = p * 256 + t;
        int n = idx >> 3, c = idx & 7;
        short8 o;
#pragma unroll
        for (int j = 0; j < 8; ++j) o[j] = (short)tile[c * 8 + j][n];
        *(short8*)(T + (size_t)(n0 + n) * 512 + k0 + ((c ^ (n & 7)) * 8)) = o;
    }
}

// ---------------------------------------------------------------------------
// Kernel 2: q/k/v projection GEMM (128x128 tile, BK=64, 4 waves). A,B staged
// via global_load_lds from pre-swizzled sources. Epilogues:
//   z==0 -> qb plain; z==1 -> kb PRE-SWIZZLED (attn K staging);
//   z==2 -> vT directly (transposed write, pre-swizzled key-chunks) -- this
//           replaces the old vtrans kernel entirely.
// ---------------------------------------------------------------------------
__global__ __launch_bounds__(256) void proj_kernel(
    const unsigned short* __restrict__ Qb, const unsigned short* __restrict__ Kb,
    const unsigned short* __restrict__ WqT, const unsigned short* __restrict__ WkT,
    const unsigned short* __restrict__ WvT,
    const float* __restrict__ bq, const float* __restrict__ bk, const float* __restrict__ bv,
    unsigned short* __restrict__ qb, unsigned short* __restrict__ kb,
    unsigned short* __restrict__ vT)
{
    const int z = blockIdx.z;
    const unsigned short* A = (z == 0) ? Qb : Kb;
    const unsigned short* WT = (z == 0) ? WqT : (z == 1) ? WkT : WvT;
    const float* bias = (z == 0) ? bq : (z == 1) ? bk : bv;

    __shared__ unsigned short Al[128 * 64];
    __shared__ unsigned short Bl[128 * 64];

    const int t = threadIdx.x;
    const int lane = t & 63, wid = t >> 6;
    const int wm = wid >> 1, wn = wid & 1;
    const int l15 = lane & 15, grp = lane >> 4;
    const int rowbase = blockIdx.y * 128;
    const int colbase = blockIdx.x * 128;
    const int srow = t >> 3, sblk = t & 7;

    f32x4 acc[4][4];
#pragma unroll
    for (int i = 0; i < 4; ++i)
#pragma unroll
        for (int j = 0; j < 4; ++j) acc[i][j] = (f32x4){0.f, 0.f, 0.f, 0.f};

    for (int kt = 0; kt < 8; ++kt) {
#pragma unroll
        for (int p = 0; p < 4; ++p)
            gl16(A + (size_t)(rowbase + p * 32 + srow) * 512 + kt * 64 + sblk * 8,
                 &Al[p * 2048 + wid * 512]);
#pragma unroll
        for (int p = 0; p < 4; ++p)
            gl16(WT + (size_t)(colbase + p * 32 + srow) * 512 + kt * 64 + sblk * 8,
                 &Bl[p * 2048 + wid * 512]);
        __syncthreads();
#pragma unroll
        for (int kk = 0; kk < 2; ++kk) {
            short8 af[4], bfr[4];
#pragma unroll
            for (int m = 0; m < 4; ++m) {
                int r = wm * 64 + m * 16 + l15;
                af[m] = *(const short8*)((const char*)Al + r * 128 + (((kk * 4 + grp) ^ (r & 7)) << 4));
            }
#pragma unroll
            for (int n = 0; n < 4; ++n) {
                int r = wn * 64 + n * 16 + l15;
                bfr[n] = *(const short8*)((const char*)Bl + r * 128 + (((kk * 4 + grp) ^ (r & 7)) << 4));
            }
#pragma unroll
            for (int m = 0; m < 4; ++m)
#pragma unroll
                for (int n = 0; n < 4; ++n)
                    acc[m][n] = MFMA16(af[m], bfr[n], acc[m][n]);
        }
        __syncthreads();
    }

    if (z == 2) {
        // v epilogue: write vT[(b*8+h)*64+d][key] transposed + pre-swizzled
#pragma unroll
        for (int n = 0; n < 4; ++n) {
            int col = colbase + wn * 64 + n * 16 + l15;
            float bvv = bias[col];
            int h_ = col >> 6, d_ = col & 63;
#pragma unroll
            for (int m = 0; m < 4; ++m) {
                int row0 = rowbase + wm * 64 + m * 16 + grp * 4;
                int b_ = row0 >> 10;
                int key0 = row0 & 1023;
                int keypos = (key0 & ~63) + ((((key0 >> 3) & 7) ^ (d_ & 7)) << 3) + (key0 & 7);
                ushort4v w;
#pragma unroll
                for (int r = 0; r < 4; ++r) w[r] = f2bf(acc[m][n][r] + bvv);
                *(ushort4v*)(vT + ((size_t)(b_ * 8 + h_) * 64 + d_) * 1024 + keypos) = w;
            }
        }
    } else {
        unsigned short* out = (z == 0) ? qb : kb;
#pragma unroll
        for (int n = 0; n < 4; ++n) {
            int col = colbase + wn * 64 + n * 16 + l15;
            float bvv = bias[col];
#pragma unroll
            for (int m = 0; m < 4; ++m) {
                int row0 = rowbase + wm * 64 + m * 16 + grp * 4;
#pragma unroll
                for (int r = 0; r < 4; ++r) {
                    int row = row0 + r;
                    int colp = (z == 1) ? (col ^ ((row & 7) << 3)) : col;
                    out[(size_t)row * 512 + colp] = f2bf(acc[m][n][r] + bvv);
                }
            }
        }
    }
}

// ---------------------------------------------------------------------------
// Kernel 3: flash attention. 256 threads = 4 waves x 32 q, Qwg=128, grid 1024
// (= 4 wg/CU, 4 independent barrier groups). Single-buffered K/V (32KB total
// LDS) staged via global_load_lds from pre-swizzled kb/vT; 2-barrier loop.
// Swapped-operand QK^T; defer-max; P via cvt_pk -> per-wave LDS; setprio
// around MFMA clusters.
// ---------------------------------------------------------------------------
__global__ __launch_bounds__(256, 4) void attn_kernel(
    const unsigned short* __restrict__ qb, const unsigned short* __restrict__ kbs,
    const unsigned short* __restrict__ vTs, unsigned short* __restrict__ Opre)
{
    __shared__ unsigned short Kl[64 * 64];    // [key][kd] swizzled
    __shared__ unsigned short Vl[64 * 64];    // [d][key] swizzled
    __shared__ unsigned short Pl[4][32 * 64]; // per-wave [q=32][key=64] swizzled

    const int t = threadIdx.x, lane = t & 63, wid = t >> 6;
    const int l15 = lane & 15, grp = lane >> 4;

    // XCD-aware decode: bid&7 = h (aligns with round-robin XCD placement);
    // within an XCD, the 8 qt-siblings of one (b,h) are adjacent -> K/V L2 hits.
    const int bid = blockIdx.x;
    const int h = bid & 7, r2 = bid >> 3;
    const int b = r2 >> 3, qt = r2 & 7;
    const int qbase = qt * 128 + wid * 32;

    // staging source addrs (per-lane); dest = wave-uniform base + lane*16
    const unsigned short* ksrc = kbs + (size_t)(b * 1024 + (t >> 3)) * 512 + h * 64 + (t & 7) * 8;
    const unsigned short* vsrc = vTs + ((size_t)(b * 8 + h) * 64 + (t >> 3)) * 1024 + (t & 7) * 8;

    // Q as B-frags
    short8 qfrag[2][2];
#pragma unroll
    for (int qf = 0; qf < 2; ++qf)
#pragma unroll
        for (int kk = 0; kk < 2; ++kk)
            qfrag[qf][kk] = *(const short8*)(
                qb + (size_t)(b * 1024 + qbase + qf * 16 + l15) * 512 + h * 64 + kk * 32 + grp * 8);

    f32x4 o[2][4];
#pragma unroll
    for (int qf = 0; qf < 2; ++qf)
#pragma unroll
        for (int df = 0; df < 4; ++df) o[qf][df] = (f32x4){0.f, 0.f, 0.f, 0.f};
    float mrun[2] = {-1e30f, -1e30f}, lrun[2] = {0.f, 0.f};

    const float C = 0.06375871f;  // (1/sqrt(512)) * log2(e)

    for (int kt = 0; kt < 16; ++kt) {
        // stage K tile [64 keys][64 kd] and V^T tile [64 d][64 keys]
#pragma unroll
        for (int p = 0; p < 2; ++p)
            gl16(ksrc + (size_t)(kt * 64 + p * 32) * 512, &Kl[p * 2048 + wid * 512]);
#pragma unroll
        for (int p = 0; p < 2; ++p)
            gl16(vsrc + p * 32768 + kt * 64, &Vl[p * 2048 + wid * 512]);
        __syncthreads();

        // S^T = K . Q^T : s[qf][nf][r] = S[key=nf*16+grp*4+r][q=l15]
        f32x4 s[2][4];
#pragma unroll
        for (int qf = 0; qf < 2; ++qf)
#pragma unroll
            for (int nf = 0; nf < 4; ++nf) s[qf][nf] = (f32x4){0.f, 0.f, 0.f, 0.f};
        __builtin_amdgcn_s_setprio(1);
#pragma unroll
        for (int kk = 0; kk < 2; ++kk) {
            short8 kf[4];
#pragma unroll
            for (int nf = 0; nf < 4; ++nf) {
                int r = nf * 16 + l15;
                kf[nf] = *(const short8*)((const char*)Kl + r * 128 + (((kk * 4 + grp) ^ (r & 7)) << 4));
            }
#pragma unroll
            for (int qf = 0; qf < 2; ++qf)
#pragma unroll
                for (int nf = 0; nf < 4; ++nf)
                    s[qf][nf] = MFMA16(kf[nf], qfrag[qf][kk], s[qf][nf]);
        }
        __builtin_amdgcn_s_setprio(0);

#pragma unroll
        for (int qf = 0; qf < 2; ++qf) {
            // balanced max tree (16 -> 1), then cross-grp
            float a0 = fmaxf(fmaxf(s[qf][0][0], s[qf][0][1]), fmaxf(s[qf][0][2], s[qf][0][3]));
            float a1 = fmaxf(fmaxf(s[qf][1][0], s[qf][1][1]), fmaxf(s[qf][1][2], s[qf][1][3]));
            float a2 = fmaxf(fmaxf(s[qf][2][0], s[qf][2][1]), fmaxf(s[qf][2][2], s[qf][2][3]));
            float a3 = fmaxf(fmaxf(s[qf][3][0], s[qf][3][1]), fmaxf(s[qf][3][2], s[qf][3][3]));
            float m = fmaxf(fmaxf(a0, a1), fmaxf(a2, a3));
            m = fmaxf(m, __shfl_xor(m, 16));
            m = fmaxf(m, __shfl_xor(m, 32));
            // defer-max: only rescale when tile max grew by > 8 (in exp2 units)
            if (__any((m - mrun[qf]) * C > 8.f)) {
                float mnew = fmaxf(mrun[qf], m);
                float rs = __builtin_amdgcn_exp2f((mrun[qf] - mnew) * C);
                mrun[qf] = mnew;
                lrun[qf] *= rs;
#pragma unroll
                for (int df = 0; df < 4; ++df)
#pragma unroll
                    for (int r = 0; r < 4; ++r) o[qf][df][r] *= rs;
            }

            int prow = qf * 16 + l15;
#pragma unroll
            for (int nf = 0; nf < 4; ++nf) {
                float p0 = __builtin_amdgcn_exp2f((s[qf][nf][0] - mrun[qf]) * C);
                float p1 = __builtin_amdgcn_exp2f((s[qf][nf][1] - mrun[qf]) * C);
                float p2 = __builtin_amdgcn_exp2f((s[qf][nf][2] - mrun[qf]) * C);
                float p3 = __builtin_amdgcn_exp2f((s[qf][nf][3] - mrun[qf]) * C);
                lrun[qf] += (p0 + p1) + (p2 + p3);
                uint2v w;
                w[0] = cvt_pk_bf16(p0, p1);
                w[1] = cvt_pk_bf16(p2, p3);
                unsigned addr = prow * 128 + (((2 * nf + (grp >> 1)) ^ (l15 & 7)) << 4) + (grp & 1) * 8;
                *(uint2v*)((char*)Pl[wid] + addr) = w;
            }
        }

        // PV transposed: o[qf][df] (= O^T[d][q]) += V^T-frag . P^T-frag
        __builtin_amdgcn_s_setprio(1);
#pragma unroll
        for (int kk = 0; kk < 2; ++kk) {
            short8 pb[2];
#pragma unroll
            for (int qf = 0; qf < 2; ++qf) {
                int prow = qf * 16 + l15;
                pb[qf] = *(const short8*)((const char*)Pl[wid] + prow * 128 + (((kk * 4 + grp) ^ (l15 & 7)) << 4));
            }
#pragma unroll
            for (int df = 0; df < 4; ++df) {
                int r = df * 16 + l15;
                short8 vf = *(const short8*)((const char*)Vl + r * 128 + (((kk * 4 + grp) ^ (r & 7)) << 4));
#pragma unroll
                for (int qf = 0; qf < 2; ++qf)
                    o[qf][df] = MFMA16(vf, pb[qf], o[qf][df]);
            }
        }
        __builtin_amdgcn_s_setprio(0);
        __syncthreads();
    }

    // epilogue: l-reduce across grp groups, normalize, add residual q, store
#pragma unroll
    for (int qf = 0; qf < 2; ++qf) {
        float l = lrun[qf];
        l += __shfl_xor(l, 16);
        l += __shfl_xor(l, 32);
        float linv = 1.f / l;
        size_t row = (size_t)(b * 1024 + qbase + qf * 16 + l15);
#pragma unroll
        for (int df = 0; df < 4; ++df) {
            int col = h * 64 + df * 16 + grp * 4;
            ushort4v res = *(const ushort4v*)(qb + row * 512 + col);
            ushort4v outv;
#pragma unroll
            for (int r = 0; r < 4; ++r)
                outv[r] = f2bf(o[qf][df][r] * linv + bf2f(res[r]));
            *(ushort4v*)(Opre + row * 512 + col) = outv;
        }
    }
}

// ---------------------------------------------------------------------------
// Kernel 4/6: LayerNorm. OUT_F32=0 writes bf16 PRE-SWIZZLED (for ffn staging);
// OUT_F32=1 writes fp32 final output.
// ---------------------------------------------------------------------------
template <int OUT_F32>
__global__ __launch_bounds__(256) void ln_kernel(
    const unsigned short* in, const float* __restrict__ g, const float* __restrict__ be,
    unsigned short* outb, float* outf)
{
    const int wid = threadIdx.x >> 6, lane = threadIdx.x & 63;
    const size_t row = (size_t)blockIdx.x * 4 + wid;
    short8 v = *(const short8*)(in + row * 512 + lane * 8);
    float x[8];
    float sum = 0.f, sq = 0.f;
#pragma unroll
    for (int j = 0; j < 8; ++j) {
        x[j] = bf2f((unsigned short)v[j]);
        sum += x[j];
        sq += x[j] * x[j];
    }
#pragma unroll
    for (int ofs = 1; ofs < 64; ofs <<= 1) {
        sum += __shfl_xor(sum, ofs);
        sq += __shfl_xor(sq, ofs);
    }
    float mean = sum * (1.f / 512.f);
    float var = sq * (1.f / 512.f) - mean * mean;
    float rs = rsqrtf(var + 1e-5f);
    float4v g0 = *(const float4v*)(g + lane * 8);
    float4v g1 = *(const float4v*)(g + lane * 8 + 4);
    float4v b0 = *(const float4v*)(be + lane * 8);
    float4v b1 = *(const float4v*)(be + lane * 8 + 4);
    float y[8];
#pragma unroll
    for (int j = 0; j < 4; ++j) y[j] = (x[j] - mean) * rs * g0[j] + b0[j];
#pragma unroll
    for (int j = 0; j < 4; ++j) y[4 + j] = (x[4 + j] - mean) * rs * g1[j] + b1[j];
    if (OUT_F32) {
        float4v o0, o1;
#pragma unroll
        for (int j = 0; j < 4; ++j) { o0[j] = y[j]; o1[j] = y[4 + j]; }
        *(float4v*)(outf + row * 512 + lane * 8) = o0;
        *(float4v*)(outf + row * 512 + lane * 8 + 4) = o1;
    } else {
        short8 o;
#pragma unroll
        for (int j = 0; j < 8; ++j) o[j] = (short)f2bf(y[j]);
        size_t op = row * 512 + (size_t)((lane >> 3) * 64 + (((lane & 7) ^ ((int)row & 7)) * 8));
        *(short8*)(outb + op) = o;
    }
}

// ---------------------------------------------------------------------------
// Kernel 5: O2 = O1 + relu(O1 @ Wo + bo). O1,WoT pre-swizzled; gload_lds stage.
// ---------------------------------------------------------------------------
__global__ __launch_bounds__(256) void ffn_kernel(
    const unsigned short* __restrict__ O1, const unsigned short* __restrict__ WoT,
    const float* __restrict__ bo, unsigned short* __restrict__ O2)
{
    __shared__ unsigned short Al[128 * 64];
    __shared__ unsigned short Bl[128 * 64];

    const int t = threadIdx.x;
    const int lane = t & 63, wid = t >> 6;
    const int wm = wid >> 1, wn = wid & 1;
    const int l15 = lane & 15, grp = lane >> 4;
    const int rowbase = blockIdx.y * 128;
    const int colbase = blockIdx.x * 128;
    const int srow = t >> 3, sblk = t & 7;

    f32x4 acc[4][4];
#pragma unroll
    for (int i = 0; i < 4; ++i)
#pragma unroll
        for (int j = 0; j < 4; ++j) acc[i][j] = (f32x4){0.f, 0.f, 0.f, 0.f};

    for (int kt = 0; kt < 8; ++kt) {
#pragma unroll
        for (int p = 0; p < 4; ++p)
            gl16(O1 + (size_t)(rowbase + p * 32 + srow) * 512 + kt * 64 + sblk * 8,
                 &Al[p * 2048 + wid * 512]);
#pragma unroll
        for (int p = 0; p < 4; ++p)
            gl16(WoT + (size_t)(colbase + p * 32 + srow) * 512 + kt * 64 + sblk * 8,
                 &Bl[p * 2048 + wid * 512]);
        __syncthreads();
#pragma unroll
        for (int kk = 0; kk < 2; ++kk) {
            short8 af[4], bfr[4];
#pragma unroll
            for (int m = 0; m < 4; ++m) {
                int r = wm * 64 + m * 16 + l15;
                af[m] = *(const short8*)((const char*)Al + r * 128 + (((kk * 4 + grp) ^ (r & 7)) << 4));
            }
#pragma unroll
            for (int n = 0; n < 4; ++n) {
                int r = wn * 64 + n * 16 + l15;
                bfr[n] = *(const short8*)((const char*)Bl + r * 128 + (((kk * 4 + grp) ^ (r & 7)) << 4));
            }
#pragma unroll
            for (int m = 0; m < 4; ++m)
#pragma unroll
                for (int n = 0; n < 4; ++n)
                    acc[m][n] = MFMA16(af[m], bfr[n], acc[m][n]);
        }
        __syncthreads();
    }
#pragma unroll
    for (int n = 0; n < 4; ++n) {
        int col = colbase + wn * 64 + n * 16 + l15;
        float bvv = bo[col];
#pragma unroll
        for (int m = 0; m < 4; ++m) {
            int row0 = rowbase + wm * 64 + m * 16 + grp * 4;
#pragma unroll
            for (int r = 0; r < 4; ++r) {
                size_t row = (size_t)(row0 + r);
                float val = fmaxf(acc[m][n][r] + bvv, 0.f);
                float resid = bf2f(O1[row * 512 + (col ^ (((int)row & 7) << 3))]);
                O2[row * 512 + col] = f2bf(resid + val);
            }
        }
    }
}

// ---------------------------------------------------------------------------
extern "C" void kernel_launch(void* const* d_in, const int* in_sizes, int n_in,
                              void* d_out, int out_size, void* d_ws, size_t ws_size,
                              hipStream_t stream)
{
    const float* Q   = (const float*)d_in[0];
    const float* Kin = (const float*)d_in[1];
    const float* Wq  = (const float*)d_in[2];
    const float* bq  = (const float*)d_in[3];
    const float* Wk  = (const float*)d_in[4];
    const float* bk  = (const float*)d_in[5];
    const float* Wv  = (const float*)d_in[6];
    const float* bv  = (const float*)d_in[7];
    const float* Wo  = (const float*)d_in[8];
    const float* bo  = (const float*)d_in[9];
    const float* g0  = (const float*)d_in[10];
    const float* b0  = (const float*)d_in[11];
    const float* g1  = (const float*)d_in[12];
    const float* b1  = (const float*)d_in[13];
    float* out = (float*)d_out;

    unsigned short* ws = (unsigned short*)d_ws;
    const size_t WSZ = 512 * 512;
    const size_t BIG = 16384 * 512;
    unsigned short* WqT  = ws;
    unsigned short* WkT  = WqT + WSZ;
    unsigned short* WvT  = WkT + WSZ;
    unsigned short* WoT  = WvT + WSZ;
    unsigned short* qb   = WoT + WSZ;
    unsigned short* kb   = qb + BIG;
    unsigned short* vT   = kb + BIG;
    unsigned short* Opre = vT + BIG;
    unsigned short* Qbf  = Opre + BIG;
    unsigned short* Kbf  = Qbf + BIG;
    unsigned short* O1   = Opre;   // LN0 in place
    unsigned short* O2   = Qbf;    // Qbf dead after proj

    cvt_kernel<<<dim3(4096, 1, 2), 256, 0, stream>>>(Q, Kin, Qbf, Kbf);
    wtrans_kernel<<<dim3(8, 8, 4), 256, 0, stream>>>(Wq, Wk, Wv, Wo, WqT, WkT, WvT, WoT);
    proj_kernel<<<dim3(4, 128, 3), 256, 0, stream>>>(Qbf, Kbf, WqT, WkT, WvT, bq, bk, bv, qb, kb, vT);
    attn_kernel<<<dim3(1024), 256, 0, stream>>>(qb, kb, vT, Opre);
    ln_kernel<0><<<dim3(4096), 256, 0, stream>>>(Opre, g0, b0, O1, nullptr);
    ffn_kernel<<<dim3(4, 128), 256, 0, stream>>>(O1, WoT, bo, O2);
    ln_kernel<1><<<dim3(4096), 256, 0, stream>>>(O2, g1, b1, nullptr, out);
}

// Round 5
// 152.739 us; speedup vs baseline: 1.3885x; 1.0762x over previous
//
#include <hip/hip_runtime.h>
#include <hip/hip_bf16.h>

typedef __attribute__((ext_vector_type(8))) short short8;
typedef __attribute__((ext_vector_type(4))) float f32x4;
typedef __attribute__((ext_vector_type(4))) float float4v;
typedef __attribute__((ext_vector_type(4))) unsigned short ushort4v;
typedef __attribute__((ext_vector_type(4))) unsigned int uint4v;

#define MFMA16(a, b, c) __builtin_amdgcn_mfma_f32_16x16x32_bf16((a), (b), (c), 0, 0, 0)

__device__ __forceinline__ unsigned short f2bf(float f) {
    union { float f; unsigned u; } v; v.f = f;
    unsigned r = v.u + 0x7fffu + ((v.u >> 16) & 1u);
    return (unsigned short)(r >> 16);
}
__device__ __forceinline__ float bf2f(unsigned short h) {
    union { unsigned u; float f; } v; v.u = (unsigned)h << 16;
    return v.f;
}
__device__ __forceinline__ unsigned cvt_pk_bf16(float lo, float hi) {
    unsigned r;
    asm("v_cvt_pk_bf16_f32 %0, %1, %2" : "=v"(r) : "v"(lo), "v"(hi));
    return r;
}
// async global->LDS, 16B per lane. LDS dest = wave-uniform base + lane*16.
__device__ __forceinline__ void gl16(const void* g, void* l) {
    __builtin_amdgcn_global_load_lds(
        (const __attribute__((address_space(1))) unsigned int*)g,
        (__attribute__((address_space(3))) unsigned int*)l, 16, 0, 0);
}

// ---------------------------------------------------------------------------
// Kernel 0: fp32 -> bf16 convert Q,K. Output PRE-SWIZZLED: within each 64-col
// block, 8-short chunk c stored at c ^ (row&7)  (so GEMM gload_lds is linear).
// ---------------------------------------------------------------------------
__global__ __launch_bounds__(256) void cvt_kernel(
    const float* __restrict__ Q, const float* __restrict__ K,
    unsigned short* __restrict__ Qb, unsigned short* __restrict__ Kb)
{
    const float* in = blockIdx.z ? K : Q;
    unsigned short* out = blockIdx.z ? Kb : Qb;
    size_t i = ((size_t)blockIdx.x * 256 + threadIdx.x) * 8;
    float4v v0 = *(const float4v*)(in + i);
    float4v v1 = *(const float4v*)(in + i + 4);
    short8 o;
#pragma unroll
    for (int j = 0; j < 4; ++j) { o[j] = (short)f2bf(v0[j]); o[4 + j] = (short)f2bf(v1[j]); }
    size_t row7 = (i >> 9) & 7;
    *(short8*)(out + (i ^ (row7 << 3))) = o;
}

// ---------------------------------------------------------------------------
// Kernel 1: weights 512x512 fp32 -> bf16 transposed, PRE-SWIZZLED rows.
// ---------------------------------------------------------------------------
__global__ __launch_bounds__(256) void wtrans_kernel(
    const float* __restrict__ W0, const float* __restrict__ W1,
    const float* __restrict__ W2, const float* __restrict__ W3,
    unsigned short* __restrict__ T0, unsigned short* __restrict__ T1,
    unsigned short* __restrict__ T2, unsigned short* __restrict__ T3)
{
    const int z = blockIdx.z;
    const float* W = (z == 0) ? W0 : (z == 1) ? W1 : (z == 2) ? W2 : W3;
    unsigned short* T = (z == 0) ? T0 : (z == 1) ? T1 : (z == 2) ? T2 : T3;

    __shared__ unsigned short tile[64][72];
    const int k0 = blockIdx.x * 64, n0 = blockIdx.y * 64;
    const int t = threadIdx.x;

#pragma unroll
    for (int p = 0; p < 4; ++p) {
        int idx = p * 256 + t;
        int k = idx >> 4, c4 = idx & 15;
        float4v v = *(const float4v*)(W + (size_t)(k0 + k) * 512 + n0 + c4 * 4);
#pragma unroll
        for (int j = 0; j < 4; ++j) tile[k][c4 * 4 + j] = f2bf(v[j]);
    }
    __syncthreads();
#pragma unroll
    for (int p = 0; p < 2; ++p) {
        int idx = p * 256 + t;
        int n = idx >> 3, c = idx & 7;
        short8 o;
#pragma unroll
        for (int j = 0; j < 8; ++j) o[j] = (short)tile[c * 8 + j][n];
        *(short8*)(T + (size_t)(n0 + n) * 512 + k0 + ((c ^ (n & 7)) * 8)) = o;
    }
}

// ---------------------------------------------------------------------------
// Kernel 2: q/k/v projection GEMM (128x128 tile, BK=64, 4 waves). A,B staged
// via global_load_lds from pre-swizzled sources. Epilogues:
//   z==0 -> qb plain;
//   z==1 -> kb with KEY-ROW PERMUTATION kappa^-1 within each 64-row block
//           (so attn's QK output rows per lane == PV's P-fragment keys) and
//           pre-swizzled columns keyed on the STORED row;
//   z==2 -> vT directly (transposed write, pre-swizzled key-chunks).
// ---------------------------------------------------------------------------
__global__ __launch_bounds__(256) void proj_kernel(
    const unsigned short* __restrict__ Qb, const unsigned short* __restrict__ Kb,
    const unsigned short* __restrict__ WqT, const unsigned short* __restrict__ WkT,
    const unsigned short* __restrict__ WvT,
    const float* __restrict__ bq, const float* __restrict__ bk, const float* __restrict__ bv,
    unsigned short* __restrict__ qb, unsigned short* __restrict__ kb,
    unsigned short* __restrict__ vT)
{
    const int z = blockIdx.z;
    const unsigned short* A = (z == 0) ? Qb : Kb;
    const unsigned short* WT = (z == 0) ? WqT : (z == 1) ? WkT : WvT;
    const float* bias = (z == 0) ? bq : (z == 1) ? bk : bv;

    __shared__ unsigned short Al[128 * 64];
    __shared__ unsigned short Bl[128 * 64];

    const int t = threadIdx.x;
    const int lane = t & 63, wid = t >> 6;
    const int wm = wid >> 1, wn = wid & 1;
    const int l15 = lane & 15, grp = lane >> 4;
    const int rowbase = blockIdx.y * 128;
    const int colbase = blockIdx.x * 128;
    const int srow = t >> 3, sblk = t & 7;

    f32x4 acc[4][4];
#pragma unroll
    for (int i = 0; i < 4; ++i)
#pragma unroll
        for (int j = 0; j < 4; ++j) acc[i][j] = (f32x4){0.f, 0.f, 0.f, 0.f};

    for (int kt = 0; kt < 8; ++kt) {
#pragma unroll
        for (int p = 0; p < 4; ++p)
            gl16(A + (size_t)(rowbase + p * 32 + srow) * 512 + kt * 64 + sblk * 8,
                 &Al[p * 2048 + wid * 512]);
#pragma unroll
        for (int p = 0; p < 4; ++p)
            gl16(WT + (size_t)(colbase + p * 32 + srow) * 512 + kt * 64 + sblk * 8,
                 &Bl[p * 2048 + wid * 512]);
        __syncthreads();
#pragma unroll
        for (int kk = 0; kk < 2; ++kk) {
            short8 af[4], bfr[4];
#pragma unroll
            for (int m = 0; m < 4; ++m) {
                int r = wm * 64 + m * 16 + l15;
                af[m] = *(const short8*)((const char*)Al + r * 128 + (((kk * 4 + grp) ^ (r & 7)) << 4));
            }
#pragma unroll
            for (int n = 0; n < 4; ++n) {
                int r = wn * 64 + n * 16 + l15;
                bfr[n] = *(const short8*)((const char*)Bl + r * 128 + (((kk * 4 + grp) ^ (r & 7)) << 4));
            }
#pragma unroll
            for (int m = 0; m < 4; ++m)
#pragma unroll
                for (int n = 0; n < 4; ++n)
                    acc[m][n] = MFMA16(af[m], bfr[n], acc[m][n]);
        }
        __syncthreads();
    }

    if (z == 2) {
        // v epilogue: write vT[(b*8+h)*64+d][key] transposed + pre-swizzled
#pragma unroll
        for (int n = 0; n < 4; ++n) {
            int col = colbase + wn * 64 + n * 16 + l15;
            float bvv = bias[col];
            int h_ = col >> 6, d_ = col & 63;
#pragma unroll
            for (int m = 0; m < 4; ++m) {
                int row0 = rowbase + wm * 64 + m * 16 + grp * 4;
                int b_ = row0 >> 10;
                int key0 = row0 & 1023;
                int keypos = (key0 & ~63) + ((((key0 >> 3) & 7) ^ (d_ & 7)) << 3) + (key0 & 7);
                ushort4v w;
#pragma unroll
                for (int r = 0; r < 4; ++r) w[r] = f2bf(acc[m][n][r] + bvv);
                *(ushort4v*)(vT + ((size_t)(b_ * 8 + h_) * 64 + d_) * 1024 + keypos) = w;
            }
        }
    } else if (z == 1) {
        // k epilogue: row-permute within 64-blocks (kappa^-1) + col swizzle by
        // stored row. kappa^-1(k): y = [k2, k5, k4, k3, k1, k0]
#pragma unroll
        for (int n = 0; n < 4; ++n) {
            int col = colbase + wn * 64 + n * 16 + l15;
            float bvv = bias[col];
#pragma unroll
            for (int m = 0; m < 4; ++m) {
                int row0 = rowbase + wm * 64 + m * 16 + grp * 4;
#pragma unroll
                for (int r = 0; r < 4; ++r) {
                    int row = row0 + r;
                    int k6 = row & 63;
                    int y = ((k6 & 4) << 3) | ((k6 & 56) >> 1) | (k6 & 3);
                    int Y = (row & ~63) | y;
                    int colp = col ^ ((y & 7) << 3);
                    kb[(size_t)Y * 512 + colp] = f2bf(acc[m][n][r] + bvv);
                }
            }
        }
    } else {
#pragma unroll
        for (int n = 0; n < 4; ++n) {
            int col = colbase + wn * 64 + n * 16 + l15;
            float bvv = bias[col];
#pragma unroll
            for (int m = 0; m < 4; ++m) {
                int row0 = rowbase + wm * 64 + m * 16 + grp * 4;
#pragma unroll
                for (int r = 0; r < 4; ++r)
                    qb[(size_t)(row0 + r) * 512 + col] = f2bf(acc[m][n][r] + bvv);
            }
        }
    }
}

// ---------------------------------------------------------------------------
// Kernel 3: flash attention. 256 threads = 4 waves x 32 q, Qwg=128, grid 1024.
// K/V double-buffered (32KB LDS), one __syncthreads per iter (stage t+1 flies
// during compute t; the barrier's vmcnt drain completes it). P stays fully
// in-register: kb's key-row permutation makes each lane's QK output rows ==
// the keys its PV P-fragment needs, so 8 cvt_pk assemble PV's B-operand.
// Static-m0 defer-max: no cross-lane softmax ops in the common path.
// ---------------------------------------------------------------------------
__global__ __launch_bounds__(256, 4) void attn_kernel(
    const unsigned short* __restrict__ qb, const unsigned short* __restrict__ kbs,
    const unsigned short* __restrict__ vTs, unsigned short* __restrict__ Opre)
{
    __shared__ unsigned short Kl[2][64 * 64];   // [key'][kd] swizzled, row-permuted
    __shared__ unsigned short Vl[2][64 * 64];   // [d][key] swizzled

    const int t = threadIdx.x, lane = t & 63, wid = t >> 6;
    const int l15 = lane & 15, grp = lane >> 4;

    // XCD-aware decode: bid&7 = h; qt-siblings of one (b,h) adjacent.
    const int bid = blockIdx.x;
    const int h = bid & 7, r2 = bid >> 3;
    const int b = r2 >> 3, qt = r2 & 7;
    const int qbase = qt * 128 + wid * 32;

    // staging source addrs (per-lane); dest = wave-uniform base + lane*16
    const unsigned short* ksrc = kbs + (size_t)(b * 1024 + (t >> 3)) * 512 + h * 64 + (t & 7) * 8;
    const unsigned short* vsrc = vTs + ((size_t)(b * 8 + h) * 64 + (t >> 3)) * 1024 + (t & 7) * 8;

#define STAGE(bsel, tile) do { \
    gl16(ksrc + (size_t)((tile) * 64) * 512,      &Kl[bsel][wid * 512]); \
    gl16(ksrc + (size_t)((tile) * 64 + 32) * 512, &Kl[bsel][2048 + wid * 512]); \
    gl16(vsrc + (tile) * 64,                      &Vl[bsel][wid * 512]); \
    gl16(vsrc + 32768 + (tile) * 64,              &Vl[bsel][2048 + wid * 512]); } while (0)

    // Q as B-frags
    short8 qfrag[2][2];
#pragma unroll
    for (int qf = 0; qf < 2; ++qf)
#pragma unroll
        for (int kk = 0; kk < 2; ++kk)
            qfrag[qf][kk] = *(const short8*)(
                qb + (size_t)(b * 1024 + qbase + qf * 16 + l15) * 512 + h * 64 + kk * 32 + grp * 8);

    f32x4 o[2][4];
#pragma unroll
    for (int qf = 0; qf < 2; ++qf)
#pragma unroll
        for (int df = 0; df < 4; ++df) o[qf][df] = (f32x4){0.f, 0.f, 0.f, 0.f};
    float mrun[2] = {0.f, 0.f}, lrun[2] = {0.f, 0.f};

    const float C = 0.06375871f;  // (1/sqrt(512)) * log2(e)

    STAGE(0, 0);
    __syncthreads();

    for (int kt = 0; kt < 16; ++kt) {
        const int buf = kt & 1;
        if (kt < 15) STAGE(buf ^ 1, kt + 1);   // flies during compute

        const char* Kb_ = (const char*)&Kl[buf][0];
        const char* Vb_ = (const char*)&Vl[buf][0];

        // S^T rows rho = nf*16+grp*4+r (key kappa(rho)), col q = l15
        f32x4 s[2][4];
#pragma unroll
        for (int qf = 0; qf < 2; ++qf)
#pragma unroll
            for (int nf = 0; nf < 4; ++nf) s[qf][nf] = (f32x4){0.f, 0.f, 0.f, 0.f};
        __builtin_amdgcn_s_setprio(1);
#pragma unroll
        for (int kk = 0; kk < 2; ++kk) {
            short8 kf[4];
#pragma unroll
            for (int nf = 0; nf < 4; ++nf) {
                int r = nf * 16 + l15;
                kf[nf] = *(const short8*)(Kb_ + r * 128 + (((kk * 4 + grp) ^ (r & 7)) << 4));
            }
#pragma unroll
            for (int qf = 0; qf < 2; ++qf)
#pragma unroll
                for (int nf = 0; nf < 4; ++nf)
                    s[qf][nf] = MFMA16(kf[nf], qfrag[qf][kk], s[qf][nf]);
        }
        __builtin_amdgcn_s_setprio(0);

        // softmax + in-register P fragments
        short8 pa[2][2];
#pragma unroll
        for (int qf = 0; qf < 2; ++qf) {
            float a0 = fmaxf(fmaxf(s[qf][0][0], s[qf][0][1]), fmaxf(s[qf][0][2], s[qf][0][3]));
            float a1 = fmaxf(fmaxf(s[qf][1][0], s[qf][1][1]), fmaxf(s[qf][1][2], s[qf][1][3]));
            float a2 = fmaxf(fmaxf(s[qf][2][0], s[qf][2][1]), fmaxf(s[qf][2][2], s[qf][2][3]));
            float a3 = fmaxf(fmaxf(s[qf][3][0], s[qf][3][1]), fmaxf(s[qf][3][2], s[qf][3][3]));
            float lm = fmaxf(fmaxf(a0, a1), fmaxf(a2, a3));
            // rare path: tile max grew past bound -> true row max + rescale
            if (__any((lm - mrun[qf]) * C > 8.f)) {
                float mr = lm;
                mr = fmaxf(mr, __shfl_xor(mr, 16));
                mr = fmaxf(mr, __shfl_xor(mr, 32));
                float mnew = fmaxf(mrun[qf], mr);
                float rs = __builtin_amdgcn_exp2f((mrun[qf] - mnew) * C);
                mrun[qf] = mnew;
                lrun[qf] *= rs;
#pragma unroll
                for (int df = 0; df < 4; ++df)
#pragma unroll
                    for (int r = 0; r < 4; ++r) o[qf][df][r] *= rs;
            }
            float nmc = -mrun[qf] * C;
            float p[4][4];
            float ls = 0.f;
#pragma unroll
            for (int nf = 0; nf < 4; ++nf)
#pragma unroll
                for (int r = 0; r < 4; ++r) {
                    p[nf][r] = __builtin_amdgcn_exp2f(fmaf(s[qf][nf][r], C, nmc));
                    ls += p[nf][r];
                }
            lrun[qf] += ls;
            union { uint4v u; short8 s8; } c0, c1;
            c0.u[0] = cvt_pk_bf16(p[0][0], p[0][1]);
            c0.u[1] = cvt_pk_bf16(p[0][2], p[0][3]);
            c0.u[2] = cvt_pk_bf16(p[2][0], p[2][1]);
            c0.u[3] = cvt_pk_bf16(p[2][2], p[2][3]);
            c1.u[0] = cvt_pk_bf16(p[1][0], p[1][1]);
            c1.u[1] = cvt_pk_bf16(p[1][2], p[1][3]);
            c1.u[2] = cvt_pk_bf16(p[3][0], p[3][1]);
            c1.u[3] = cvt_pk_bf16(p[3][2], p[3][3]);
            pa[qf][0] = c0.s8;
            pa[qf][1] = c1.s8;
        }

        // PV: o^T[d][q] += V^T-frag . P^T-frag (P^T straight from registers)
        __builtin_amdgcn_s_setprio(1);
#pragma unroll
        for (int kk = 0; kk < 2; ++kk)
#pragma unroll
            for (int df = 0; df < 4; ++df) {
                int r = df * 16 + l15;
                short8 vf = *(const short8*)(Vb_ + r * 128 + (((kk * 4 + grp) ^ (r & 7)) << 4));
#pragma unroll
                for (int qf = 0; qf < 2; ++qf)
                    o[qf][df] = MFMA16(vf, pa[qf][kk], o[qf][df]);
            }
        __builtin_amdgcn_s_setprio(0);
        __syncthreads();
    }
#undef STAGE

    // epilogue: l-reduce across grp groups, normalize, add residual q, store
#pragma unroll
    for (int qf = 0; qf < 2; ++qf) {
        float l = lrun[qf];
        l += __shfl_xor(l, 16);
        l += __shfl_xor(l, 32);
        float linv = 1.f / l;
        size_t row = (size_t)(b * 1024 + qbase + qf * 16 + l15);
#pragma unroll
        for (int df = 0; df < 4; ++df) {
            int col = h * 64 + df * 16 + grp * 4;
            ushort4v res = *(const ushort4v*)(qb + row * 512 + col);
            ushort4v outv;
#pragma unroll
            for (int r = 0; r < 4; ++r)
                outv[r] = f2bf(o[qf][df][r] * linv + bf2f(res[r]));
            *(ushort4v*)(Opre + row * 512 + col) = outv;
        }
    }
}

// ---------------------------------------------------------------------------
// Kernel 4/6: LayerNorm. OUT_F32=0 writes bf16 PRE-SWIZZLED (for ffn staging);
// OUT_F32=1 writes fp32 final output.
// ---------------------------------------------------------------------------
template <int OUT_F32>
__global__ __launch_bounds__(256) void ln_kernel(
    const unsigned short* in, const float* __restrict__ g, const float* __restrict__ be,
    unsigned short* outb, float* outf)
{
    const int wid = threadIdx.x >> 6, lane = threadIdx.x & 63;
    const size_t row = (size_t)blockIdx.x * 4 + wid;
    short8 v = *(const short8*)(in + row * 512 + lane * 8);
    float x[8];
    float sum = 0.f, sq = 0.f;
#pragma unroll
    for (int j = 0; j < 8; ++j) {
        x[j] = bf2f((unsigned short)v[j]);
        sum += x[j];
        sq += x[j] * x[j];
    }
#pragma unroll
    for (int ofs = 1; ofs < 64; ofs <<= 1) {
        sum += __shfl_xor(sum, ofs);
        sq += __shfl_xor(sq, ofs);
    }
    float mean = sum * (1.f / 512.f);
    float var = sq * (1.f / 512.f) - mean * mean;
    float rs = rsqrtf(var + 1e-5f);
    float4v g0 = *(const float4v*)(g + lane * 8);
    float4v g1 = *(const float4v*)(g + lane * 8 + 4);
    float4v b0 = *(const float4v*)(be + lane * 8);
    float4v b1 = *(const float4v*)(be + lane * 8 + 4);
    float y[8];
#pragma unroll
    for (int j = 0; j < 4; ++j) y[j] = (x[j] - mean) * rs * g0[j] + b0[j];
#pragma unroll
    for (int j = 0; j < 4; ++j) y[4 + j] = (x[4 + j] - mean) * rs * g1[j] + b1[j];
    if (OUT_F32) {
        float4v o0, o1;
#pragma unroll
        for (int j = 0; j < 4; ++j) { o0[j] = y[j]; o1[j] = y[4 + j]; }
        *(float4v*)(outf + row * 512 + lane * 8) = o0;
        *(float4v*)(outf + row * 512 + lane * 8 + 4) = o1;
    } else {
        short8 o;
#pragma unroll
        for (int j = 0; j < 8; ++j) o[j] = (short)f2bf(y[j]);
        size_t op = row * 512 + (size_t)((lane >> 3) * 64 + (((lane & 7) ^ ((int)row & 7)) * 8));
        *(short8*)(outb + op) = o;
    }
}

// ---------------------------------------------------------------------------
// Kernel 5: O2 = O1 + relu(O1 @ Wo + bo). O1,WoT pre-swizzled; gload_lds stage.
// ---------------------------------------------------------------------------
__global__ __launch_bounds__(256) void ffn_kernel(
    const unsigned short* __restrict__ O1, const unsigned short* __restrict__ WoT,
    const float* __restrict__ bo, unsigned short* __restrict__ O2)
{
    __shared__ unsigned short Al[128 * 64];
    __shared__ unsigned short Bl[128 * 64];

    const int t = threadIdx.x;
    const int lane = t & 63, wid = t >> 6;
    const int wm = wid >> 1, wn = wid & 1;
    const int l15 = lane & 15, grp = lane >> 4;
    const int rowbase = blockIdx.y * 128;
    const int colbase = blockIdx.x * 128;
    const int srow = t >> 3, sblk = t & 7;

    f32x4 acc[4][4];
#pragma unroll
    for (int i = 0; i < 4; ++i)
#pragma unroll
        for (int j = 0; j < 4; ++j) acc[i][j] = (f32x4){0.f, 0.f, 0.f, 0.f};

    for (int kt = 0; kt < 8; ++kt) {
#pragma unroll
        for (int p = 0; p < 4; ++p)
            gl16(O1 + (size_t)(rowbase + p * 32 + srow) * 512 + kt * 64 + sblk * 8,
                 &Al[p * 2048 + wid * 512]);
#pragma unroll
        for (int p = 0; p < 4; ++p)
            gl16(WoT + (size_t)(colbase + p * 32 + srow) * 512 + kt * 64 + sblk * 8,
                 &Bl[p * 2048 + wid * 512]);
        __syncthreads();
#pragma unroll
        for (int kk = 0; kk < 2; ++kk) {
            short8 af[4], bfr[4];
#pragma unroll
            for (int m = 0; m < 4; ++m) {
                int r = wm * 64 + m * 16 + l15;
                af[m] = *(const short8*)((const char*)Al + r * 128 + (((kk * 4 + grp) ^ (r & 7)) << 4));
            }
#pragma unroll
            for (int n = 0; n < 4; ++n) {
                int r = wn * 64 + n * 16 + l15;
                bfr[n] = *(const short8*)((const char*)Bl + r * 128 + (((kk * 4 + grp) ^ (r & 7)) << 4));
            }
#pragma unroll
            for (int m = 0; m < 4; ++m)
#pragma unroll
                for (int n = 0; n < 4; ++n)
                    acc[m][n] = MFMA16(af[m], bfr[n], acc[m][n]);
        }
        __syncthreads();
    }
#pragma unroll
    for (int n = 0; n < 4; ++n) {
        int col = colbase + wn * 64 + n * 16 + l15;
        float bvv = bo[col];
#pragma unroll
        for (int m = 0; m < 4; ++m) {
            int row0 = rowbase + wm * 64 + m * 16 + grp * 4;
#pragma unroll
            for (int r = 0; r < 4; ++r) {
                size_t row = (size_t)(row0 + r);
                float val = fmaxf(acc[m][n][r] + bvv, 0.f);
                float resid = bf2f(O1[row * 512 + (col ^ (((int)row & 7) << 3))]);
                O2[row * 512 + col] = f2bf(resid + val);
            }
        }
    }
}

// ---------------------------------------------------------------------------
extern "C" void kernel_launch(void* const* d_in, const int* in_sizes, int n_in,
                              void* d_out, int out_size, void* d_ws, size_t ws_size,
                              hipStream_t stream)
{
    const float* Q   = (const float*)d_in[0];
    const float* Kin = (const float*)d_in[1];
    const float* Wq  = (const float*)d_in[2];
    const float* bq  = (const float*)d_in[3];
    const float* Wk  = (const float*)d_in[4];
    const float* bk  = (const float*)d_in[5];
    const float* Wv  = (const float*)d_in[6];
    const float* bv  = (const float*)d_in[7];
    const float* Wo  = (const float*)d_in[8];
    const float* bo  = (const float*)d_in[9];
    const float* g0  = (const float*)d_in[10];
    const float* b0  = (const float*)d_in[11];
    const float* g1  = (const float*)d_in[12];
    const float* b1  = (const float*)d_in[13];
    float* out = (float*)d_out;

    unsigned short* ws = (unsigned short*)d_ws;
    const size_t WSZ = 512 * 512;
    const size_t BIG = 16384 * 512;
    unsigned short* WqT  = ws;
    unsigned short* WkT  = WqT + WSZ;
    unsigned short* WvT  = WkT + WSZ;
    unsigned short* WoT  = WvT + WSZ;
    unsigned short* qb   = WoT + WSZ;
    unsigned short* kb   = qb + BIG;
    unsigned short* vT   = kb + BIG;
    unsigned short* Opre = vT + BIG;
    unsigned short* Qbf  = Opre + BIG;
    unsigned short* Kbf  = Qbf + BIG;
    unsigned short* O1   = Opre;   // LN0 in place
    unsigned short* O2   = Qbf;    // Qbf dead after proj

    cvt_kernel<<<dim3(4096, 1, 2), 256, 0, stream>>>(Q, Kin, Qbf, Kbf);
    wtrans_kernel<<<dim3(8, 8, 4), 256, 0, stream>>>(Wq, Wk, Wv, Wo, WqT, WkT, WvT, WoT);
    proj_kernel<<<dim3(4, 128, 3), 256, 0, stream>>>(Qbf, Kbf, WqT, WkT, WvT, bq, bk, bv, qb, kb, vT);
    attn_kernel<<<dim3(1024), 256, 0, stream>>>(qb, kb, vT, Opre);
    ln_kernel<0><<<dim3(4096), 256, 0, stream>>>(Opre, g0, b0, O1, nullptr);
    ffn_kernel<<<dim3(4, 128), 256, 0, stream>>>(O1, WoT, bo, O2);
    ln_kernel<1><<<dim3(4096), 256, 0, stream>>>(O2, g1, b1, nullptr, out);
}